// Round 11
// baseline (2843.901 us; speedup 1.0000x reference)
//
#include <hip/hip_runtime.h>
#include <stdint.h>

#define BATCH 4096
#define DIM   1024
#define PPREV 8
#define CAPW  64    // per-wave candidate capacity

// popcount of mask over lanes strictly below the current lane
__device__ __forceinline__ int lt_count(unsigned long long m) {
    return __builtin_amdgcn_mbcnt_hi((unsigned)(m >> 32),
           __builtin_amdgcn_mbcnt_lo((unsigned)m, 0));
}
__device__ __forceinline__ bool kp_gt(int ak, int ap, int bk, int bp) {
    return (ak > bk) || (ak == bk && ap > bp);
}

// ============================================================================
// Block-cooperative top-10 by |value|, exact jax.lax.top_k tie-break (lowest
// flat index wins among ties). 256 threads/row; thread owns j = tid*4+t.
// Key = |f32 bits| (int compare == magnitude compare);
// payload = ((1023-j)<<1)|sign -> (key,pay) lex-desc == (value desc, idx asc).
// ============================================================================
template<bool SEEDED>
__device__ __forceinline__ void select10_blk(
    const float cz[4], int tid, int lane, int wid,
    int2 (*s_cand)[CAPW], int2* s_win, int* s_cnt, int2* s_red, int* s_bnd,
    int& tbits, int wi[10], float wv[10])
{
    int k[4], pay[4];
    #pragma unroll
    for (int t = 0; t < 4; ++t) {
        int bb = __float_as_int(cz[t]);
        k[t]   = bb & 0x7fffffff;
        pay[t] = ((1023 - (tid * 4 + t)) << 1) | (int)((unsigned)bb >> 31);
    }

    if (!SEEDED) {
        int lm = max(max(k[0], k[1]), max(k[2], k[3]));
        #pragma unroll
        for (int k2 = 2; k2 <= 64; k2 <<= 1) {
            #pragma unroll
            for (int j = k2 >> 1; j > 0; j >>= 1) {
                int p = __shfl_xor(lm, j);
                bool keep_max = (((lane & k2) == 0) == ((lane & j) == 0));
                if ((p > lm) == keep_max) lm = p;
            }
        }
        int wb = __builtin_amdgcn_readlane(lm, 9);
        if (lane == 0) s_bnd[wid] = wb;
        __syncthreads();
        tbits = max(max(s_bnd[0], s_bnd[1]), max(s_bnd[2], s_bnd[3]));
    }

    int tb = tbits;
    int c0, c1, c2, c3, total; bool bad;
    #pragma unroll 1
    for (;;) {
        unsigned long long b0 = __ballot(k[0] >= tb);
        unsigned long long b1 = __ballot(k[1] >= tb);
        unsigned long long b2 = __ballot(k[2] >= tb);
        unsigned long long b3 = __ballot(k[3] >= tb);
        int pos = lt_count(b0);
        if (k[0] >= tb && pos < CAPW) s_cand[wid][pos] = make_int2(k[0], pay[0]);
        int base = __popcll(b0);
        pos = base + lt_count(b1);
        if (k[1] >= tb && pos < CAPW) s_cand[wid][pos] = make_int2(k[1], pay[1]);
        base += __popcll(b1);
        pos = base + lt_count(b2);
        if (k[2] >= tb && pos < CAPW) s_cand[wid][pos] = make_int2(k[2], pay[2]);
        base += __popcll(b2);
        pos = base + lt_count(b3);
        if (k[3] >= tb && pos < CAPW) s_cand[wid][pos] = make_int2(k[3], pay[3]);
        base += __popcll(b3);
        if (lane == 0) s_cnt[wid] = base;
        __syncthreads();                               // barrier 1
        c0 = s_cnt[0]; c1 = s_cnt[1]; c2 = s_cnt[2]; c3 = s_cnt[3];
        total = c0 + c1 + c2 + c3;
        bad = (c0 > CAPW) || (c1 > CAPW) || (c2 > CAPW) || (c3 > CAPW);
        if (total >= 10 || tb == 0) break;
        tb = (tb > 0x00800000) ? (tb - 0x00800000) : 0;
        __syncthreads();
    }

    if (!bad) {
        if (tid < total) {
            int w, e;
            if      (tid < c0)           { w = 0; e = tid; }
            else if (tid < c0 + c1)      { w = 1; e = tid - c0; }
            else if (tid < c0 + c1 + c2) { w = 2; e = tid - c0 - c1; }
            else                         { w = 3; e = tid - c0 - c1 - c2; }
            int2 mine = s_cand[w][e];
            int cns[4] = {c0, c1, c2, c3};
            int rank = 0;
            #pragma unroll
            for (int w2 = 0; w2 < 4; ++w2) {
                const int cn = cns[w2];
                const int2* reg = s_cand[w2];
                int e2 = 0;
                #pragma unroll 1
                for (; e2 + 4 <= cn; e2 += 4) {
                    int2 q0 = reg[e2], q1 = reg[e2+1], q2 = reg[e2+2], q3 = reg[e2+3];
                    rank += kp_gt(q0.x, q0.y, mine.x, mine.y) ? 1 : 0;
                    rank += kp_gt(q1.x, q1.y, mine.x, mine.y) ? 1 : 0;
                    rank += kp_gt(q2.x, q2.y, mine.x, mine.y) ? 1 : 0;
                    rank += kp_gt(q3.x, q3.y, mine.x, mine.y) ? 1 : 0;
                }
                #pragma unroll 1
                for (; e2 < cn; ++e2) {
                    int2 q = reg[e2];
                    rank += kp_gt(q.x, q.y, mine.x, mine.y) ? 1 : 0;
                }
            }
            if (rank < 10) s_win[rank] = mine;
        }
        __syncthreads();                               // barrier 2
    } else {
        #pragma unroll 1
        for (int r = 0; r < 10; ++r) {
            int bk = k[0], bp = pay[0];
            #pragma unroll
            for (int t = 1; t < 4; ++t)
                if (kp_gt(k[t], pay[t], bk, bp)) { bk = k[t]; bp = pay[t]; }
            #pragma unroll
            for (int m = 1; m < 64; m <<= 1) {
                int ok = __shfl_xor(bk, m), op = __shfl_xor(bp, m);
                if (kp_gt(ok, op, bk, bp)) { bk = ok; bp = op; }
            }
            if (lane == 0) s_red[wid] = make_int2(bk, bp);
            __syncthreads();
            if (tid == 0) {
                int2 best = s_red[0];
                #pragma unroll
                for (int w2 = 1; w2 < 4; ++w2) {
                    int2 cc = s_red[w2];
                    if (kp_gt(cc.x, cc.y, best.x, best.y)) best = cc;
                }
                s_win[r] = best;
            }
            __syncthreads();
            int2 wr = s_win[r];
            #pragma unroll
            for (int t = 0; t < 4; ++t)
                if (k[t] == wr.x && pay[t] == wr.y) k[t] = -1;
        }
    }

    #pragma unroll
    for (int r = 0; r < 10; ++r) {
        int2 wr = s_win[r];
        wi[r] = 1023 - (wr.y >> 1);
        wv[r] = __int_as_float(wr.x | ((wr.y & 1) << 31));
    }
    tbits = __float_as_int(wv[9]) & 0x7fffffff;
}

// c = b + sum_k wv[k] * S[wi[k], :]
__device__ __forceinline__ void gather_block(const float bz[4], float cz[4],
                                             const float* __restrict__ S,
                                             const int wi[10], const float wv[10], int tid)
{
    #pragma unroll
    for (int t = 0; t < 4; ++t) cz[t] = bz[t];
    #pragma unroll
    for (int kk = 0; kk < 10; ++kk) {
        int row = __builtin_amdgcn_readfirstlane(wi[kk]);
        const float wvs = wv[kk];
        float4 v = *(const float4*)(S + (size_t)row * DIM + tid * 4);
        cz[0] += wvs * v.x;
        cz[1] += wvs * v.y;
        cz[2] += wvs * v.z;
        cz[3] += wvs * v.w;
    }
}

// ============================================================================
// Warm-up rows
// ============================================================================
__global__ __launch_bounds__(256)
void warmup_rows(const float* __restrict__ b, const float* __restrict__ S,
                 int* __restrict__ sidx, float* __restrict__ sval)
{
    __shared__ int2 s_cand[4][CAPW];
    __shared__ int2 s_win[10];
    __shared__ int2 s_red[4];
    __shared__ int  s_cnt[4];
    __shared__ int  s_bnd[4];
    const int tid = threadIdx.x, lane = tid & 63, wid = tid >> 6;
    const int r = blockIdx.x;
    float4 bv = *(const float4*)(b + (size_t)r * DIM + tid * 4);
    float bz[4] = {bv.x, bv.y, bv.z, bv.w};
    int wi[10]; float wv[10]; int tbits = 0;
    select10_blk<false>(bz, tid, lane, wid, s_cand, s_win, s_cnt, s_red, s_bnd, tbits, wi, wv);
    float cz[4];
    gather_block(bz, cz, S, wi, wv, tid);
    select10_blk<true>(cz, tid, lane, wid, s_cand, s_win, s_cnt, s_red, s_bnd, tbits, wi, wv);
    if (tid < 10) {
        int2 wr = s_win[tid];
        sidx[r * 10 + tid] = 1023 - (wr.y >> 1);
        sval[r * 10 + tid] = __int_as_float(wr.x | ((wr.y & 1) << 31));
    }
}

// ============================================================================
// Main loop rows
// ============================================================================
__global__ __launch_bounds__(256)
void loop_rows(const float* __restrict__ c1, const float* __restrict__ b,
               const float* __restrict__ S, float* __restrict__ zout,
               int* __restrict__ sidx, float* __restrict__ sval)
{
    __shared__ int2 s_cand[4][CAPW];
    __shared__ int2 s_win[10];
    __shared__ int2 s_red[4];
    __shared__ int  s_cnt[4];
    __shared__ int  s_bnd[4];
    const int tid = threadIdx.x, lane = tid & 63, wid = tid >> 6;
    const int r = blockIdx.x;
    float4 bv = *(const float4*)(b  + (size_t)r * DIM + tid * 4);
    float4 cv = *(const float4*)(c1 + (size_t)r * DIM + tid * 4);
    float bz[4] = {bv.x, bv.y, bv.z, bv.w};
    float cz[4] = {cv.x, cv.y, cv.z, cv.w};
    int wi[10]; float wv[10]; int tbits = 0;
    select10_blk<false>(cz, tid, lane, wid, s_cand, s_win, s_cnt, s_red, s_bnd, tbits, wi, wv);
    int pwi[10], pwb[10];
    #pragma unroll 1
    for (int it = 0; it < 9; ++it) {
        #pragma unroll
        for (int kk = 0; kk < 10; ++kk) { pwi[kk] = wi[kk]; pwb[kk] = __float_as_int(wv[kk]); }
        gather_block(bz, cz, S, wi, wv, tid);
        select10_blk<true>(cz, tid, lane, wid, s_cand, s_win, s_cnt, s_red, s_bnd, tbits, wi, wv);
        bool same = true;
        #pragma unroll
        for (int kk = 0; kk < 10; ++kk)
            same = same && (wi[kk] == pwi[kk]) && (__float_as_int(wv[kk]) == pwb[kk]);
        if (same) break;
    }
    float e[4];
    #pragma unroll
    for (int t = 0; t < 4; ++t) {
        const int j = tid * 4 + t;
        float v = 0.0f;
        #pragma unroll
        for (int kk = 0; kk < 10; ++kk) v = (wi[kk] == j) ? wv[kk] : v;
        e[t] = v;
    }
    float4 o; o.x = e[0]; o.y = e[1]; o.z = e[2]; o.w = e[3];
    *(float4*)(zout + (size_t)r * DIM + tid * 4) = o;
    if (tid < 10) {
        int2 wr = s_win[tid];
        sidx[r * 10 + tid] = 1023 - (wr.y >> 1);
        sval[r * 10 + tid] = __int_as_float(wr.x | ((wr.y & 1) << 31));
    }
}

// ============================================================================
// GEMM: 128x128 tile, BK=16, 512 threads = 8 waves (2x4 wave grid, 8x8 lane
// grid, 8x4/thread), cmap conflict-free multicast LDS reads, double-buffered,
// ONE barrier per K-tile, register prefetch.
// RAW=true: write bare partial over [k_begin, k_begin+k_count) (split-K).
// __launch_bounds__(512,4): cap VGPR<=128 so TWO blocks co-reside per CU.
// ============================================================================
template<bool DIV_L, bool HAS_ADD, bool RAW>
__global__ __launch_bounds__(512, 4)
void gemm512(const float* __restrict__ A, const float* __restrict__ B,
             const float* __restrict__ addM, float* __restrict__ C,
             const float* __restrict__ Lptr, int M, int N, int K,
             int k_count)
{
    __shared__ __align__(16) float As[2][16][140];
    __shared__ __align__(16) float Bs[2][16][140];
    const int tid  = threadIdx.x;
    const int lane = tid & 63, w = tid >> 6;
    const int wy = lane >> 3, wx = lane & 7;
    const int mq = w >> 2, nq = w & 3;
    const int m0 = blockIdx.y * 128, n0 = blockIdx.x * 128;
    const int k_begin = blockIdx.z * k_count;

    const int srow = tid >> 2;
    const int sk   = (tid & 3) * 4;
    const int scol = srow + ((srow >> 5) << 2);

    const int am_ = mq * 64 + wy * 8;
    const int aoff = am_ + ((am_ >> 5) << 2);
    const int bn_ = nq * 32 + wx * 4;
    const int boff = bn_ + ((bn_ >> 5) << 2);

    const float* Ab = A + (size_t)(m0 + srow) * K + sk + k_begin;
    const float* Bb = B + (size_t)(n0 + srow) * K + sk + k_begin;

    float acc[8][4] = {};

    float4 ra = *(const float4*)(Ab);
    float4 rb = *(const float4*)(Bb);

    const int NT = k_count / 16;
    {
        float* ap = &As[0][sk][scol];
        ap[0*140]=ra.x; ap[1*140]=ra.y; ap[2*140]=ra.z; ap[3*140]=ra.w;
        float* bp = &Bs[0][sk][scol];
        bp[0*140]=rb.x; bp[1*140]=rb.y; bp[2*140]=rb.z; bp[3*140]=rb.w;
    }
    __syncthreads();

    #pragma unroll 1
    for (int t = 0; t < NT; ++t) {
        const int cur = t & 1;
        if (t + 1 < NT) {
            const int ko = (t + 1) * 16;
            ra = *(const float4*)(Ab + ko);
            rb = *(const float4*)(Bb + ko);
        }
        #pragma unroll
        for (int k = 0; k < 16; ++k) {
            float4 a40 = *(const float4*)&As[cur][k][aoff];
            float4 a41 = *(const float4*)&As[cur][k][aoff + 4];
            float4 b40 = *(const float4*)&Bs[cur][k][boff];
            float am[8] = {a40.x,a40.y,a40.z,a40.w,a41.x,a41.y,a41.z,a41.w};
            float bn[4] = {b40.x,b40.y,b40.z,b40.w};
            #pragma unroll
            for (int i = 0; i < 8; ++i)
                #pragma unroll
                for (int j = 0; j < 4; ++j)
                    acc[i][j] += am[i] * bn[j];
        }
        if (t + 1 < NT) {
            const int nxt = (t + 1) & 1;
            float* ap = &As[nxt][sk][scol];
            ap[0*140]=ra.x; ap[1*140]=ra.y; ap[2*140]=ra.z; ap[3*140]=ra.w;
            float* bp = &Bs[nxt][sk][scol];
            bp[0*140]=rb.x; bp[1*140]=rb.y; bp[2*140]=rb.z; bp[3*140]=rb.w;
            __syncthreads();
        }
    }

    float* Cout = C + (RAW ? (size_t)blockIdx.z * M * N : 0);
    const float invL = (DIV_L && !RAW) ? (1.0f / *Lptr) : 1.0f;
    #pragma unroll
    for (int i = 0; i < 8; ++i) {
        size_t row = (size_t)(m0 + mq*64 + wy*8 + i);
        float* Cp = Cout + row * N + n0 + nq*32 + wx*4;
        float4 rv;
        rv.x=acc[i][0]; rv.y=acc[i][1]; rv.z=acc[i][2]; rv.w=acc[i][3];
        if (DIV_L && !RAW) { rv.x*=invL; rv.y*=invL; rv.z*=invL; rv.w*=invL; }
        if (HAS_ADD && !RAW) {
            float4 ad = *(const float4*)(addM + row * N + n0 + nq*32 + wx*4);
            rv.x+=ad.x; rv.y+=ad.y; rv.z+=ad.z; rv.w+=ad.w;
        }
        *(float4*)(Cp) = rv;
    }
}

// ============================================================================
// Split-K epilogues: out = (p0+p1)/L   and   out = p0+p1+add
// ============================================================================
__global__ __launch_bounds__(256)
void epi_scale(const float* __restrict__ p0, const float* __restrict__ p1,
               const float* __restrict__ Lptr, float* __restrict__ out)
{
    const size_t i = ((size_t)blockIdx.x * 256 + threadIdx.x) * 4;
    const float s = 1.0f / *Lptr;
    float4 a = *(const float4*)(p0 + i);
    float4 b = *(const float4*)(p1 + i);
    float4 r;
    r.x = (a.x + b.x) * s; r.y = (a.y + b.y) * s;
    r.z = (a.z + b.z) * s; r.w = (a.w + b.w) * s;
    *(float4*)(out + i) = r;
}

__global__ __launch_bounds__(256)
void epi_add(const float* __restrict__ p0, const float* __restrict__ p1,
             const float* __restrict__ add, float* __restrict__ out)
{
    const size_t i = ((size_t)blockIdx.x * 256 + threadIdx.x) * 4;
    float4 a = *(const float4*)(p0 + i);
    float4 b = *(const float4*)(p1 + i);
    float4 c = *(const float4*)(add + i);
    float4 r;
    r.x = a.x + b.x + c.x; r.y = a.y + b.y + c.y;
    r.z = a.z + b.z + c.z; r.w = a.w + b.w + c.w;
    *(float4*)(out + i) = r;
}

// ============================================================================
// Spectral density from sparse z
// ============================================================================
__global__ void sparse_density_stage1(const int* __restrict__ sidx,
                                      const float* __restrict__ sval,
                                      float* __restrict__ partial)
{
    const int w = threadIdx.x;
    const int blk = blockIdx.x;
    const int base = blk * 64 * 10;
    float acc = 0.0f;
    for (int e = 0; e < 640; ++e) {
        int d = sidx[base + e];
        float v = sval[base + e];
        if ((d & 511) == w) acc += v * v;
    }
    partial[blk * 512 + w] = acc;
}

// ============================================================================
// prev_windows spectral density
// ============================================================================
__global__ void prev_density_stage1(const float* __restrict__ pw, float* __restrict__ partial)
{
    const int p = blockIdx.x, chunk = blockIdx.y;
    const int w = threadIdx.x;
    const float* base = pw + ((size_t)p * BATCH + (size_t)chunk * 64) * DIM;
    float acc = 0.0f;
    for (int i = 0; i < 64; ++i) {
        float a = base[(size_t)i * DIM + w];
        float c = base[(size_t)i * DIM + 512 + w];
        acc += a * a + c * c;
    }
    partial[((size_t)(p * 64 + chunk)) * 512 + w] = acc;
}

__global__ void prev_density_stage2(const float* __restrict__ partial, float* __restrict__ mD_prev)
{
    const int p = blockIdx.x; const int w = threadIdx.x;
    float acc = 0.0f;
    for (int i = 0; i < 64; ++i) acc += partial[((size_t)(p * 64 + i)) * 512 + w];
    mD_prev[p * 512 + w] = acc;
}

// ============================================================================
// Fused: mD1 col-sum; normalize; attention logits; softmax.
// ============================================================================
__device__ __forceinline__ float wave_fmax(float v) {
    #pragma unroll
    for (int m = 1; m < 64; m <<= 1) v = fmaxf(v, __shfl_xor(v, m));
    return v;
}
__device__ __forceinline__ float wave_fmin(float v) {
    #pragma unroll
    for (int m = 1; m < 64; m <<= 1) v = fminf(v, __shfl_xor(v, m));
    return v;
}
__device__ __forceinline__ float wave_fsum(float v) {
    #pragma unroll
    for (int m = 1; m < 64; m <<= 1) v += __shfl_xor(v, m);
    return v;
}

__global__ void density2_attention(const float* __restrict__ partial,
                                   const float* __restrict__ mD_prev,
                                   float* __restrict__ att)
{
    __shared__ float md1[512];
    __shared__ float att_l[PPREV];
    const int tid = threadIdx.x, lane = tid & 63, w = tid >> 6;
    float v = 0.0f;
    for (int i = 0; i < 64; ++i) v += partial[i * 512 + tid];
    md1[tid] = v;
    __syncthreads();
    float t8[8], u8[8];
    {
        const float4* m4 = (const float4*)(&md1[lane * 8]);
        float4 a = m4[0], bq = m4[1];
        t8[0]=a.x; t8[1]=a.y; t8[2]=a.z; t8[3]=a.w; t8[4]=bq.x; t8[5]=bq.y; t8[6]=bq.z; t8[7]=bq.w;
        const float4* p4 = (const float4*)(mD_prev + w * 512 + lane * 8);
        float4 c = p4[0], d = p4[1];
        u8[0]=c.x; u8[1]=c.y; u8[2]=c.z; u8[3]=c.w; u8[4]=d.x; u8[5]=d.y; u8[6]=d.z; u8[7]=d.w;
    }
    float mx = t8[0], mn = t8[0], pmx = u8[0], pmn = u8[0];
    #pragma unroll
    for (int i = 1; i < 8; ++i) {
        mx = fmaxf(mx, t8[i]); mn = fminf(mn, t8[i]);
        pmx = fmaxf(pmx, u8[i]); pmn = fminf(pmn, u8[i]);
    }
    mx = wave_fmax(mx); mn = wave_fmin(mn);
    pmx = wave_fmax(pmx); pmn = wave_fmin(pmn);
    const float inv  = 1.0f / (mx - mn + 1e-8f);
    const float pinv = 1.0f / (pmx - pmn + 1e-8f);
    float dot = 0.0f;
    #pragma unroll
    for (int i = 0; i < 8; ++i) dot += ((u8[i] - pmn) * pinv) * ((t8[i] - mn) * inv);
    dot = wave_fsum(dot);
    if (lane == 0) att_l[w] = dot / 22.627417f;   // np.float32(sqrt(512))
    __syncthreads();
    if (tid == 0) {
        float m = att_l[0];
        #pragma unroll
        for (int p = 1; p < PPREV; ++p) m = fmaxf(m, att_l[p]);
        float e[PPREV], s = 0.0f;
        #pragma unroll
        for (int p = 0; p < PPREV; ++p) { e[p] = expf(att_l[p] - m); s += e[p]; }
        #pragma unroll
        for (int p = 0; p < PPREV; ++p) att[p] = e[p] / s;
    }
}

// ============================================================================
// z_att = lambda2 * sum_p clip(pw[p], +-150) * att[p]
// ============================================================================
__global__ __launch_bounds__(256)
void weighted_sum(const float* __restrict__ pw, const float* __restrict__ att,
                  const float* __restrict__ lam, float* __restrict__ zatt)
{
    const size_t i = ((size_t)blockIdx.x * 256 + threadIdx.x) * 4;
    const float l2 = *lam;
    float a[PPREV];
    #pragma unroll
    for (int p = 0; p < PPREV; ++p) a[p] = att[p];
    float4 acc = make_float4(0.f, 0.f, 0.f, 0.f);
    #pragma unroll
    for (int p = 0; p < PPREV; ++p) {
        float4 v = *(const float4*)(pw + (size_t)p * BATCH * DIM + i);
        v.x = fminf(fmaxf(v.x, -150.f), 150.f);
        v.y = fminf(fmaxf(v.y, -150.f), 150.f);
        v.z = fminf(fmaxf(v.z, -150.f), 150.f);
        v.w = fminf(fmaxf(v.w, -150.f), 150.f);
        acc.x += v.x * a[p]; acc.y += v.y * a[p]; acc.z += v.z * a[p]; acc.w += v.w * a[p];
    }
    acc.x *= l2; acc.y *= l2; acc.z *= l2; acc.w *= l2;
    *(float4*)(zatt + i) = acc;
}

// ============================================================================
// Final: mD2 col-sum + min-max normalize into out[0:512]
// ============================================================================
__global__ void finalize_fused(const float* __restrict__ partial, float* __restrict__ out)
{
    __shared__ float red[512];
    const int tid = threadIdx.x;
    float v = 0.0f;
    for (int i = 0; i < 64; ++i) v += partial[i * 512 + tid];
    red[tid] = v; __syncthreads();
    for (int off = 256; off > 0; off >>= 1) { if (tid < off) red[tid] = fmaxf(red[tid], red[tid+off]); __syncthreads(); }
    float mx = red[0]; __syncthreads();
    red[tid] = v; __syncthreads();
    for (int off = 256; off > 0; off >>= 1) { if (tid < off) red[tid] = fminf(red[tid], red[tid+off]); __syncthreads(); }
    float mn = red[0];
    out[tid] = (v - mn) / (mx - mn + 1e-8f);
}

// ============================================================================
extern "C" void kernel_launch(void* const* d_in, const int* in_sizes, int n_in,
                              void* d_out, int out_size, void* d_ws, size_t ws_size,
                              hipStream_t stream)
{
    const float* x   = (const float*)d_in[0];   // [4096,1024]
    const float* pw  = (const float*)d_in[1];   // [8,4096,1024]
    const float* Wd  = (const float*)d_in[2];   // [1,1024,1024]
    const float* S   = (const float*)d_in[3];   // [1,1024,1024] (numerically symmetric)
    const float* lam = (const float*)d_in[4];   // scalar
    const float* L   = (const float*)d_in[5];   // scalar
    float* out = (float*)d_out;                 // [512] ++ [4096*1024]

    const size_t NE = (size_t)BATCH * DIM;              // 4,194,304

    float* b       = (float*)d_ws;                      // NE
    float* zatt    = b + NE;                            // NE
    float* pp_prev = zatt + NE;                         // 262,144
    float* pp_dens = pp_prev + 262144;                  // 32,768
    float* mD_prev = pp_dens + 32768;                   // 4096
    float* attw    = mD_prev + 4096;                    // 8
    float* sval1   = attw + 8;                          // 40,960
    float* sval2   = sval1 + 40960;                     // 40,960
    int*   sidx1   = (int*)(sval2 + 40960);             // 40,960 ints
    int*   sidx2   = sidx1 + 40960;                     // 40,960 ints
    float* parts   = (float*)(sidx2 + 40960);           // 2*NE (split-K partials)

    const size_t need_bytes = ((char*)(parts + 2 * NE)) - (char*)d_ws;
    const bool splitk = (ws_size >= need_bytes);

    float* c1   = out + 512;
    float* zout = out + 512;

    if (splitk) {
        const dim3 g3(DIM / 128, BATCH / 128, 2);       // 512 blocks, 2 K-slices
        // b = x @ Wd^T / L  (partials + epilogue)
        gemm512<false, false, true ><<<g3, 512, 0, stream>>>(x, Wd, nullptr, parts, nullptr, BATCH, DIM, DIM, DIM / 2);
        epi_scale<<<(int)(NE / 1024), 256, 0, stream>>>(parts, parts + NE, L, b);
        warmup_rows<<<BATCH, 256, 0, stream>>>(b, S, sidx1, sval1);
        sparse_density_stage1<<<64, 512, 0, stream>>>(sidx1, sval1, pp_dens);
        prev_density_stage1<<<dim3(PPREV, 64), 512, 0, stream>>>(pw, pp_prev);
        prev_density_stage2<<<PPREV, 512, 0, stream>>>(pp_prev, mD_prev);
        density2_attention<<<1, 512, 0, stream>>>(pp_dens, mD_prev, attw);
        weighted_sum<<<(int)(NE / 1024), 256, 0, stream>>>(pw, attw, lam, zatt);
        // c1 = b + zatt @ S^T  (partials + epilogue)
        gemm512<false, false, true ><<<g3, 512, 0, stream>>>(zatt, S, nullptr, parts, nullptr, BATCH, DIM, DIM, DIM / 2);
        epi_add<<<(int)(NE / 1024), 256, 0, stream>>>(parts, parts + NE, b, c1);
        loop_rows<<<BATCH, 256, 0, stream>>>(c1, b, S, zout, sidx2, sval2);
        sparse_density_stage1<<<64, 512, 0, stream>>>(sidx2, sval2, pp_dens);
        finalize_fused<<<1, 512, 0, stream>>>(pp_dens, out);
    } else {
        const dim3 gg(DIM / 128, BATCH / 128, 1);       // 256 blocks (round-10 path)
        gemm512<true,  false, false><<<gg, 512, 0, stream>>>(x, Wd, nullptr, b, L, BATCH, DIM, DIM, DIM);
        warmup_rows<<<BATCH, 256, 0, stream>>>(b, S, sidx1, sval1);
        sparse_density_stage1<<<64, 512, 0, stream>>>(sidx1, sval1, pp_dens);
        prev_density_stage1<<<dim3(PPREV, 64), 512, 0, stream>>>(pw, pp_prev);
        prev_density_stage2<<<PPREV, 512, 0, stream>>>(pp_prev, mD_prev);
        density2_attention<<<1, 512, 0, stream>>>(pp_dens, mD_prev, attw);
        weighted_sum<<<(int)(NE / 1024), 256, 0, stream>>>(pw, attw, lam, zatt);
        gemm512<false, true,  false><<<gg, 512, 0, stream>>>(zatt, S, b, c1, nullptr, BATCH, DIM, DIM, DIM);
        loop_rows<<<BATCH, 256, 0, stream>>>(c1, b, S, zout, sidx2, sval2);
        sparse_density_stage1<<<64, 512, 0, stream>>>(sidx2, sval2, pp_dens);
        finalize_fused<<<1, 512, 0, stream>>>(pp_dens, out);
    }
}

// Round 12
// 2332.544 us; speedup vs baseline: 1.2192x; 1.2192x over previous
//
#include <hip/hip_runtime.h>
#include <stdint.h>

#define BATCH 4096
#define DIM   1024
#define PPREV 8
#define CAPW  64    // per-wave candidate capacity

// popcount of mask over lanes strictly below the current lane
__device__ __forceinline__ int lt_count(unsigned long long m) {
    return __builtin_amdgcn_mbcnt_hi((unsigned)(m >> 32),
           __builtin_amdgcn_mbcnt_lo((unsigned)m, 0));
}
__device__ __forceinline__ bool kp_gt(int ak, int ap, int bk, int bp) {
    return (ak > bk) || (ak == bk && ap > bp);
}

// ============================================================================
// Block-cooperative top-10 by |value|, exact jax.lax.top_k tie-break (lowest
// flat index wins among ties). 256 threads/row; thread owns j = tid*4+t.
// Key = |f32 bits| (int compare == magnitude compare);
// payload = ((1023-j)<<1)|sign -> (key,pay) lex-desc == (value desc, idx asc).
// ============================================================================
template<bool SEEDED>
__device__ __forceinline__ void select10_blk(
    const float cz[4], int tid, int lane, int wid,
    int2 (*s_cand)[CAPW], int2* s_win, int* s_cnt, int2* s_red, int* s_bnd,
    int& tbits, int wi[10], float wv[10])
{
    int k[4], pay[4];
    #pragma unroll
    for (int t = 0; t < 4; ++t) {
        int bb = __float_as_int(cz[t]);
        k[t]   = bb & 0x7fffffff;
        pay[t] = ((1023 - (tid * 4 + t)) << 1) | (int)((unsigned)bb >> 31);
    }

    if (!SEEDED) {
        int lm = max(max(k[0], k[1]), max(k[2], k[3]));
        #pragma unroll
        for (int k2 = 2; k2 <= 64; k2 <<= 1) {
            #pragma unroll
            for (int j = k2 >> 1; j > 0; j >>= 1) {
                int p = __shfl_xor(lm, j);
                bool keep_max = (((lane & k2) == 0) == ((lane & j) == 0));
                if ((p > lm) == keep_max) lm = p;
            }
        }
        int wb = __builtin_amdgcn_readlane(lm, 9);
        if (lane == 0) s_bnd[wid] = wb;
        __syncthreads();
        tbits = max(max(s_bnd[0], s_bnd[1]), max(s_bnd[2], s_bnd[3]));
    }

    int tb = tbits;
    int c0, c1, c2, c3, total; bool bad;
    #pragma unroll 1
    for (;;) {
        unsigned long long b0 = __ballot(k[0] >= tb);
        unsigned long long b1 = __ballot(k[1] >= tb);
        unsigned long long b2 = __ballot(k[2] >= tb);
        unsigned long long b3 = __ballot(k[3] >= tb);
        int pos = lt_count(b0);
        if (k[0] >= tb && pos < CAPW) s_cand[wid][pos] = make_int2(k[0], pay[0]);
        int base = __popcll(b0);
        pos = base + lt_count(b1);
        if (k[1] >= tb && pos < CAPW) s_cand[wid][pos] = make_int2(k[1], pay[1]);
        base += __popcll(b1);
        pos = base + lt_count(b2);
        if (k[2] >= tb && pos < CAPW) s_cand[wid][pos] = make_int2(k[2], pay[2]);
        base += __popcll(b2);
        pos = base + lt_count(b3);
        if (k[3] >= tb && pos < CAPW) s_cand[wid][pos] = make_int2(k[3], pay[3]);
        base += __popcll(b3);
        if (lane == 0) s_cnt[wid] = base;
        __syncthreads();                               // barrier 1
        c0 = s_cnt[0]; c1 = s_cnt[1]; c2 = s_cnt[2]; c3 = s_cnt[3];
        total = c0 + c1 + c2 + c3;
        bad = (c0 > CAPW) || (c1 > CAPW) || (c2 > CAPW) || (c3 > CAPW);
        if (total >= 10 || tb == 0) break;
        tb = (tb > 0x00800000) ? (tb - 0x00800000) : 0;
        __syncthreads();
    }

    if (!bad) {
        if (tid < total) {
            int w, e;
            if      (tid < c0)           { w = 0; e = tid; }
            else if (tid < c0 + c1)      { w = 1; e = tid - c0; }
            else if (tid < c0 + c1 + c2) { w = 2; e = tid - c0 - c1; }
            else                         { w = 3; e = tid - c0 - c1 - c2; }
            int2 mine = s_cand[w][e];
            int cns[4] = {c0, c1, c2, c3};
            int rank = 0;
            #pragma unroll
            for (int w2 = 0; w2 < 4; ++w2) {
                const int cn = cns[w2];
                const int2* reg = s_cand[w2];
                int e2 = 0;
                #pragma unroll 1
                for (; e2 + 4 <= cn; e2 += 4) {
                    int2 q0 = reg[e2], q1 = reg[e2+1], q2 = reg[e2+2], q3 = reg[e2+3];
                    rank += kp_gt(q0.x, q0.y, mine.x, mine.y) ? 1 : 0;
                    rank += kp_gt(q1.x, q1.y, mine.x, mine.y) ? 1 : 0;
                    rank += kp_gt(q2.x, q2.y, mine.x, mine.y) ? 1 : 0;
                    rank += kp_gt(q3.x, q3.y, mine.x, mine.y) ? 1 : 0;
                }
                #pragma unroll 1
                for (; e2 < cn; ++e2) {
                    int2 q = reg[e2];
                    rank += kp_gt(q.x, q.y, mine.x, mine.y) ? 1 : 0;
                }
            }
            if (rank < 10) s_win[rank] = mine;
        }
        __syncthreads();                               // barrier 2
    } else {
        #pragma unroll 1
        for (int r = 0; r < 10; ++r) {
            int bk = k[0], bp = pay[0];
            #pragma unroll
            for (int t = 1; t < 4; ++t)
                if (kp_gt(k[t], pay[t], bk, bp)) { bk = k[t]; bp = pay[t]; }
            #pragma unroll
            for (int m = 1; m < 64; m <<= 1) {
                int ok = __shfl_xor(bk, m), op = __shfl_xor(bp, m);
                if (kp_gt(ok, op, bk, bp)) { bk = ok; bp = op; }
            }
            if (lane == 0) s_red[wid] = make_int2(bk, bp);
            __syncthreads();
            if (tid == 0) {
                int2 best = s_red[0];
                #pragma unroll
                for (int w2 = 1; w2 < 4; ++w2) {
                    int2 cc = s_red[w2];
                    if (kp_gt(cc.x, cc.y, best.x, best.y)) best = cc;
                }
                s_win[r] = best;
            }
            __syncthreads();
            int2 wr = s_win[r];
            #pragma unroll
            for (int t = 0; t < 4; ++t)
                if (k[t] == wr.x && pay[t] == wr.y) k[t] = -1;
        }
    }

    #pragma unroll
    for (int r = 0; r < 10; ++r) {
        int2 wr = s_win[r];
        wi[r] = 1023 - (wr.y >> 1);
        wv[r] = __int_as_float(wr.x | ((wr.y & 1) << 31));
    }
    tbits = __float_as_int(wv[9]) & 0x7fffffff;
}

// c = b + sum_k wv[k] * S[wi[k], :]
__device__ __forceinline__ void gather_block(const float bz[4], float cz[4],
                                             const float* __restrict__ S,
                                             const int wi[10], const float wv[10], int tid)
{
    #pragma unroll
    for (int t = 0; t < 4; ++t) cz[t] = bz[t];
    #pragma unroll
    for (int kk = 0; kk < 10; ++kk) {
        int row = __builtin_amdgcn_readfirstlane(wi[kk]);
        const float wvs = wv[kk];
        float4 v = *(const float4*)(S + (size_t)row * DIM + tid * 4);
        cz[0] += wvs * v.x;
        cz[1] += wvs * v.y;
        cz[2] += wvs * v.z;
        cz[3] += wvs * v.w;
    }
}

// ============================================================================
// Warm-up rows
// ============================================================================
__global__ __launch_bounds__(256)
void warmup_rows(const float* __restrict__ b, const float* __restrict__ S,
                 int* __restrict__ sidx, float* __restrict__ sval)
{
    __shared__ int2 s_cand[4][CAPW];
    __shared__ int2 s_win[10];
    __shared__ int2 s_red[4];
    __shared__ int  s_cnt[4];
    __shared__ int  s_bnd[4];
    const int tid = threadIdx.x, lane = tid & 63, wid = tid >> 6;
    const int r = blockIdx.x;
    float4 bv = *(const float4*)(b + (size_t)r * DIM + tid * 4);
    float bz[4] = {bv.x, bv.y, bv.z, bv.w};
    int wi[10]; float wv[10]; int tbits = 0;
    select10_blk<false>(bz, tid, lane, wid, s_cand, s_win, s_cnt, s_red, s_bnd, tbits, wi, wv);
    float cz[4];
    gather_block(bz, cz, S, wi, wv, tid);
    select10_blk<true>(cz, tid, lane, wid, s_cand, s_win, s_cnt, s_red, s_bnd, tbits, wi, wv);
    if (tid < 10) {
        int2 wr = s_win[tid];
        sidx[r * 10 + tid] = 1023 - (wr.y >> 1);
        sval[r * 10 + tid] = __int_as_float(wr.x | ((wr.y & 1) << 31));
    }
}

// ============================================================================
// Main loop rows
// ============================================================================
__global__ __launch_bounds__(256)
void loop_rows(const float* __restrict__ c1, const float* __restrict__ b,
               const float* __restrict__ S, float* __restrict__ zout,
               int* __restrict__ sidx, float* __restrict__ sval)
{
    __shared__ int2 s_cand[4][CAPW];
    __shared__ int2 s_win[10];
    __shared__ int2 s_red[4];
    __shared__ int  s_cnt[4];
    __shared__ int  s_bnd[4];
    const int tid = threadIdx.x, lane = tid & 63, wid = tid >> 6;
    const int r = blockIdx.x;
    float4 bv = *(const float4*)(b  + (size_t)r * DIM + tid * 4);
    float4 cv = *(const float4*)(c1 + (size_t)r * DIM + tid * 4);
    float bz[4] = {bv.x, bv.y, bv.z, bv.w};
    float cz[4] = {cv.x, cv.y, cv.z, cv.w};
    int wi[10]; float wv[10]; int tbits = 0;
    select10_blk<false>(cz, tid, lane, wid, s_cand, s_win, s_cnt, s_red, s_bnd, tbits, wi, wv);
    int pwi[10], pwb[10];
    #pragma unroll 1
    for (int it = 0; it < 9; ++it) {
        #pragma unroll
        for (int kk = 0; kk < 10; ++kk) { pwi[kk] = wi[kk]; pwb[kk] = __float_as_int(wv[kk]); }
        gather_block(bz, cz, S, wi, wv, tid);
        select10_blk<true>(cz, tid, lane, wid, s_cand, s_win, s_cnt, s_red, s_bnd, tbits, wi, wv);
        bool same = true;
        #pragma unroll
        for (int kk = 0; kk < 10; ++kk)
            same = same && (wi[kk] == pwi[kk]) && (__float_as_int(wv[kk]) == pwb[kk]);
        if (same) break;
    }
    float e[4];
    #pragma unroll
    for (int t = 0; t < 4; ++t) {
        const int j = tid * 4 + t;
        float v = 0.0f;
        #pragma unroll
        for (int kk = 0; kk < 10; ++kk) v = (wi[kk] == j) ? wv[kk] : v;
        e[t] = v;
    }
    float4 o; o.x = e[0]; o.y = e[1]; o.z = e[2]; o.w = e[3];
    *(float4*)(zout + (size_t)r * DIM + tid * 4) = o;
    if (tid < 10) {
        int2 wr = s_win[tid];
        sidx[r * 10 + tid] = 1023 - (wr.y >> 1);
        sval[r * 10 + tid] = __int_as_float(wr.x | ((wr.y & 1) << 31));
    }
}

// ============================================================================
// GEMM: C[m,n] = (sum_k A[m,k]*B[n,k]) [/L] [+ add[m,n]]  (C = A @ B^T)
// 128x128 tile, BK=32 (half the barriers of BK=16), 512 threads = 8 waves
// (2x4 wave grid, 8x8 lane grid, 8x4/thread). cmap(m)=m+(m>>5)*4 column
// placement: both operand reads are 8-address multicast hitting distinct
// bank quads (conflict-free). Double-buffered, ONE barrier per K-tile,
// register prefetch. Grid 256 = 1 block/CU; NO min-waves clause (round-11's
// (512,4) capped VGPR at 64 and spilled everything to scratch).
// ============================================================================
template<bool DIV_L, bool HAS_ADD>
__global__ __launch_bounds__(512)
void gemm512(const float* __restrict__ A, const float* __restrict__ B,
             const float* __restrict__ addM, float* __restrict__ C,
             const float* __restrict__ Lptr, int M, int N, int K)
{
    __shared__ __align__(16) float As[2][32][140];
    __shared__ __align__(16) float Bs[2][32][140];
    const int tid  = threadIdx.x;
    const int lane = tid & 63, w = tid >> 6;
    const int wy = lane >> 3, wx = lane & 7;
    const int mq = w >> 2, nq = w & 3;
    const int m0 = blockIdx.y * 128, n0 = blockIdx.x * 128;

    const int srow = tid >> 2;                       // 0..127
    const int sk   = (tid & 3) * 4;                  // 0,4,8,12 (and +16)
    const int scol = srow + ((srow >> 5) << 2);      // cmap(srow)

    const int am_ = mq * 64 + wy * 8;
    const int aoff = am_ + ((am_ >> 5) << 2);
    const int bn_ = nq * 32 + wx * 4;
    const int boff = bn_ + ((bn_ >> 5) << 2);

    const float* Ab = A + (size_t)(m0 + srow) * K + sk;
    const float* Bb = B + (size_t)(n0 + srow) * K + sk;

    float acc[8][4] = {};

    float4 ra0 = *(const float4*)(Ab);
    float4 ra1 = *(const float4*)(Ab + 16);
    float4 rb0 = *(const float4*)(Bb);
    float4 rb1 = *(const float4*)(Bb + 16);

    const int NT = K / 32;
    {   // stage tile 0 (two k-halves per operand)
        float* ap0 = &As[0][sk][scol];
        ap0[0*140]=ra0.x; ap0[1*140]=ra0.y; ap0[2*140]=ra0.z; ap0[3*140]=ra0.w;
        float* ap1 = &As[0][sk+16][scol];
        ap1[0*140]=ra1.x; ap1[1*140]=ra1.y; ap1[2*140]=ra1.z; ap1[3*140]=ra1.w;
        float* bp0 = &Bs[0][sk][scol];
        bp0[0*140]=rb0.x; bp0[1*140]=rb0.y; bp0[2*140]=rb0.z; bp0[3*140]=rb0.w;
        float* bp1 = &Bs[0][sk+16][scol];
        bp1[0*140]=rb1.x; bp1[1*140]=rb1.y; bp1[2*140]=rb1.z; bp1[3*140]=rb1.w;
    }
    __syncthreads();

    #pragma unroll 1
    for (int t = 0; t < NT; ++t) {
        const int cur = t & 1;
        if (t + 1 < NT) {                  // next-tile loads issue under FMAs
            const int ko = (t + 1) * 32;
            ra0 = *(const float4*)(Ab + ko);
            ra1 = *(const float4*)(Ab + ko + 16);
            rb0 = *(const float4*)(Bb + ko);
            rb1 = *(const float4*)(Bb + ko + 16);
        }
        #pragma unroll
        for (int k = 0; k < 32; ++k) {
            float4 a40 = *(const float4*)&As[cur][k][aoff];
            float4 a41 = *(const float4*)&As[cur][k][aoff + 4];
            float4 b40 = *(const float4*)&Bs[cur][k][boff];
            float am[8] = {a40.x,a40.y,a40.z,a40.w,a41.x,a41.y,a41.z,a41.w};
            float bn[4] = {b40.x,b40.y,b40.z,b40.w};
            #pragma unroll
            for (int i = 0; i < 8; ++i)
                #pragma unroll
                for (int j = 0; j < 4; ++j)
                    acc[i][j] += am[i] * bn[j];
        }
        if (t + 1 < NT) {                  // stage OTHER buffer; single barrier
            const int nxt = (t + 1) & 1;
            float* ap0 = &As[nxt][sk][scol];
            ap0[0*140]=ra0.x; ap0[1*140]=ra0.y; ap0[2*140]=ra0.z; ap0[3*140]=ra0.w;
            float* ap1 = &As[nxt][sk+16][scol];
            ap1[0*140]=ra1.x; ap1[1*140]=ra1.y; ap1[2*140]=ra1.z; ap1[3*140]=ra1.w;
            float* bp0 = &Bs[nxt][sk][scol];
            bp0[0*140]=rb0.x; bp0[1*140]=rb0.y; bp0[2*140]=rb0.z; bp0[3*140]=rb0.w;
            float* bp1 = &Bs[nxt][sk+16][scol];
            bp1[0*140]=rb1.x; bp1[1*140]=rb1.y; bp1[2*140]=rb1.z; bp1[3*140]=rb1.w;
            __syncthreads();
        }
    }

    const float invL = DIV_L ? (1.0f / *Lptr) : 1.0f;
    #pragma unroll
    for (int i = 0; i < 8; ++i) {
        size_t row = (size_t)(m0 + mq*64 + wy*8 + i);
        float* Cp = C + row * N + n0 + nq*32 + wx*4;
        float4 rv;
        rv.x=acc[i][0]; rv.y=acc[i][1]; rv.z=acc[i][2]; rv.w=acc[i][3];
        if (DIV_L) { rv.x*=invL; rv.y*=invL; rv.z*=invL; rv.w*=invL; }
        if (HAS_ADD) {
            float4 ad = *(const float4*)(addM + row * N + n0 + nq*32 + wx*4);
            rv.x+=ad.x; rv.y+=ad.y; rv.z+=ad.z; rv.w+=ad.w;
        }
        *(float4*)(Cp) = rv;
    }
}

// ============================================================================
// Spectral density from sparse z
// ============================================================================
__global__ void sparse_density_stage1(const int* __restrict__ sidx,
                                      const float* __restrict__ sval,
                                      float* __restrict__ partial)
{
    const int w = threadIdx.x;
    const int blk = blockIdx.x;
    const int base = blk * 64 * 10;
    float acc = 0.0f;
    for (int e = 0; e < 640; ++e) {
        int d = sidx[base + e];
        float v = sval[base + e];
        if ((d & 511) == w) acc += v * v;
    }
    partial[blk * 512 + w] = acc;
}

// ============================================================================
// prev_windows spectral density
// ============================================================================
__global__ void prev_density_stage1(const float* __restrict__ pw, float* __restrict__ partial)
{
    const int p = blockIdx.x, chunk = blockIdx.y;
    const int w = threadIdx.x;
    const float* base = pw + ((size_t)p * BATCH + (size_t)chunk * 64) * DIM;
    float acc = 0.0f;
    for (int i = 0; i < 64; ++i) {
        float a = base[(size_t)i * DIM + w];
        float c = base[(size_t)i * DIM + 512 + w];
        acc += a * a + c * c;
    }
    partial[((size_t)(p * 64 + chunk)) * 512 + w] = acc;
}

__global__ void prev_density_stage2(const float* __restrict__ partial, float* __restrict__ mD_prev)
{
    const int p = blockIdx.x; const int w = threadIdx.x;
    float acc = 0.0f;
    for (int i = 0; i < 64; ++i) acc += partial[((size_t)(p * 64 + i)) * 512 + w];
    mD_prev[p * 512 + w] = acc;
}

// ============================================================================
// Fused: mD1 col-sum; normalize; attention logits; softmax.
// ============================================================================
__device__ __forceinline__ float wave_fmax(float v) {
    #pragma unroll
    for (int m = 1; m < 64; m <<= 1) v = fmaxf(v, __shfl_xor(v, m));
    return v;
}
__device__ __forceinline__ float wave_fmin(float v) {
    #pragma unroll
    for (int m = 1; m < 64; m <<= 1) v = fminf(v, __shfl_xor(v, m));
    return v;
}
__device__ __forceinline__ float wave_fsum(float v) {
    #pragma unroll
    for (int m = 1; m < 64; m <<= 1) v += __shfl_xor(v, m);
    return v;
}

__global__ void density2_attention(const float* __restrict__ partial,
                                   const float* __restrict__ mD_prev,
                                   float* __restrict__ att)
{
    __shared__ float md1[512];
    __shared__ float att_l[PPREV];
    const int tid = threadIdx.x, lane = tid & 63, w = tid >> 6;
    float v = 0.0f;
    for (int i = 0; i < 64; ++i) v += partial[i * 512 + tid];
    md1[tid] = v;
    __syncthreads();
    float t8[8], u8[8];
    {
        const float4* m4 = (const float4*)(&md1[lane * 8]);
        float4 a = m4[0], bq = m4[1];
        t8[0]=a.x; t8[1]=a.y; t8[2]=a.z; t8[3]=a.w; t8[4]=bq.x; t8[5]=bq.y; t8[6]=bq.z; t8[7]=bq.w;
        const float4* p4 = (const float4*)(mD_prev + w * 512 + lane * 8);
        float4 c = p4[0], d = p4[1];
        u8[0]=c.x; u8[1]=c.y; u8[2]=c.z; u8[3]=c.w; u8[4]=d.x; u8[5]=d.y; u8[6]=d.z; u8[7]=d.w;
    }
    float mx = t8[0], mn = t8[0], pmx = u8[0], pmn = u8[0];
    #pragma unroll
    for (int i = 1; i < 8; ++i) {
        mx = fmaxf(mx, t8[i]); mn = fminf(mn, t8[i]);
        pmx = fmaxf(pmx, u8[i]); pmn = fminf(pmn, u8[i]);
    }
    mx = wave_fmax(mx); mn = wave_fmin(mn);
    pmx = wave_fmax(pmx); pmn = wave_fmin(pmn);
    const float inv  = 1.0f / (mx - mn + 1e-8f);
    const float pinv = 1.0f / (pmx - pmn + 1e-8f);
    float dot = 0.0f;
    #pragma unroll
    for (int i = 0; i < 8; ++i) dot += ((u8[i] - pmn) * pinv) * ((t8[i] - mn) * inv);
    dot = wave_fsum(dot);
    if (lane == 0) att_l[w] = dot / 22.627417f;   // np.float32(sqrt(512))
    __syncthreads();
    if (tid == 0) {
        float m = att_l[0];
        #pragma unroll
        for (int p = 1; p < PPREV; ++p) m = fmaxf(m, att_l[p]);
        float e[PPREV], s = 0.0f;
        #pragma unroll
        for (int p = 0; p < PPREV; ++p) { e[p] = expf(att_l[p] - m); s += e[p]; }
        #pragma unroll
        for (int p = 0; p < PPREV; ++p) att[p] = e[p] / s;
    }
}

// ============================================================================
// z_att = lambda2 * sum_p clip(pw[p], +-150) * att[p]
// ============================================================================
__global__ __launch_bounds__(256)
void weighted_sum(const float* __restrict__ pw, const float* __restrict__ att,
                  const float* __restrict__ lam, float* __restrict__ zatt)
{
    const size_t i = ((size_t)blockIdx.x * 256 + threadIdx.x) * 4;
    const float l2 = *lam;
    float a[PPREV];
    #pragma unroll
    for (int p = 0; p < PPREV; ++p) a[p] = att[p];
    float4 acc = make_float4(0.f, 0.f, 0.f, 0.f);
    #pragma unroll
    for (int p = 0; p < PPREV; ++p) {
        float4 v = *(const float4*)(pw + (size_t)p * BATCH * DIM + i);
        v.x = fminf(fmaxf(v.x, -150.f), 150.f);
        v.y = fminf(fmaxf(v.y, -150.f), 150.f);
        v.z = fminf(fmaxf(v.z, -150.f), 150.f);
        v.w = fminf(fmaxf(v.w, -150.f), 150.f);
        acc.x += v.x * a[p]; acc.y += v.y * a[p]; acc.z += v.z * a[p]; acc.w += v.w * a[p];
    }
    acc.x *= l2; acc.y *= l2; acc.z *= l2; acc.w *= l2;
    *(float4*)(zatt + i) = acc;
}

// ============================================================================
// Final: mD2 col-sum + min-max normalize into out[0:512]
// ============================================================================
__global__ void finalize_fused(const float* __restrict__ partial, float* __restrict__ out)
{
    __shared__ float red[512];
    const int tid = threadIdx.x;
    float v = 0.0f;
    for (int i = 0; i < 64; ++i) v += partial[i * 512 + tid];
    red[tid] = v; __syncthreads();
    for (int off = 256; off > 0; off >>= 1) { if (tid < off) red[tid] = fmaxf(red[tid], red[tid+off]); __syncthreads(); }
    float mx = red[0]; __syncthreads();
    red[tid] = v; __syncthreads();
    for (int off = 256; off > 0; off >>= 1) { if (tid < off) red[tid] = fminf(red[tid], red[tid+off]); __syncthreads(); }
    float mn = red[0];
    out[tid] = (v - mn) / (mx - mn + 1e-8f);
}

// ============================================================================
extern "C" void kernel_launch(void* const* d_in, const int* in_sizes, int n_in,
                              void* d_out, int out_size, void* d_ws, size_t ws_size,
                              hipStream_t stream)
{
    const float* x   = (const float*)d_in[0];   // [4096,1024]
    const float* pw  = (const float*)d_in[1];   // [8,4096,1024]
    const float* Wd  = (const float*)d_in[2];   // [1,1024,1024]
    const float* S   = (const float*)d_in[3];   // [1,1024,1024] (numerically symmetric)
    const float* lam = (const float*)d_in[4];   // scalar
    const float* L   = (const float*)d_in[5];   // scalar
    float* out = (float*)d_out;                 // [512] ++ [4096*1024]

    const size_t NE = (size_t)BATCH * DIM;              // 4,194,304

    float* b       = (float*)d_ws;                      // NE
    float* zatt    = b + NE;                            // NE
    float* pp_prev = zatt + NE;                         // 262,144
    float* pp_dens = pp_prev + 262144;                  // 32,768
    float* mD_prev = pp_dens + 32768;                   // 4096
    float* attw    = mD_prev + 4096;                    // 8
    float* sval1   = attw + 8;                          // 40,960
    float* sval2   = sval1 + 40960;                     // 40,960
    int*   sidx1   = (int*)(sval2 + 40960);             // 40,960 ints
    int*   sidx2   = sidx1 + 40960;                     // 40,960 ints

    float* c1   = out + 512;
    float* zout = out + 512;

    const dim3 gg(DIM / 128, BATCH / 128);   // (8, 32) = 256 blocks = 1/CU

    gemm512<true,  false><<<gg, 512, 0, stream>>>(x, Wd, nullptr, b, L, BATCH, DIM, DIM);
    warmup_rows<<<BATCH, 256, 0, stream>>>(b, S, sidx1, sval1);
    sparse_density_stage1<<<64, 512, 0, stream>>>(sidx1, sval1, pp_dens);
    prev_density_stage1<<<dim3(PPREV, 64), 512, 0, stream>>>(pw, pp_prev);
    prev_density_stage2<<<PPREV, 512, 0, stream>>>(pp_prev, mD_prev);
    density2_attention<<<1, 512, 0, stream>>>(pp_dens, mD_prev, attw);
    weighted_sum<<<(int)(NE / 1024), 256, 0, stream>>>(pw, attw, lam, zatt);
    gemm512<false, true ><<<gg, 512, 0, stream>>>(zatt, S, b, c1, nullptr, BATCH, DIM, DIM);
    loop_rows<<<BATCH, 256, 0, stream>>>(c1, b, S, zout, sidx2, sval2);
    sparse_density_stage1<<<64, 512, 0, stream>>>(sidx2, sval2, pp_dens);
    finalize_fused<<<1, 512, 0, stream>>>(pp_dens, out);
}

// Round 13
// 517.818 us; speedup vs baseline: 5.4921x; 4.5046x over previous
//
#include <hip/hip_runtime.h>
#include <stdint.h>

#define BATCH 4096
#define DIM   1024
#define PPREV 8
#define CAPW  64    // per-wave candidate capacity

// popcount of mask over lanes strictly below the current lane
__device__ __forceinline__ int lt_count(unsigned long long m) {
    return __builtin_amdgcn_mbcnt_hi((unsigned)(m >> 32),
           __builtin_amdgcn_mbcnt_lo((unsigned)m, 0));
}
__device__ __forceinline__ bool kp_gt(int ak, int ap, int bk, int bp) {
    return (ak > bk) || (ak == bk && ap > bp);
}

// ============================================================================
// Block-cooperative top-10 by |value|, exact jax.lax.top_k tie-break (lowest
// flat index wins among ties). 256 threads/row; thread owns j = tid*4+t.
// Key = |f32 bits| (int compare == magnitude compare);
// payload = ((1023-j)<<1)|sign -> (key,pay) lex-desc == (value desc, idx asc).
// ============================================================================
template<bool SEEDED>
__device__ __forceinline__ void select10_blk(
    const float cz[4], int tid, int lane, int wid,
    int2 (*s_cand)[CAPW], int2* s_win, int* s_cnt, int2* s_red, int* s_bnd,
    int& tbits, int wi[10], float wv[10])
{
    int k[4], pay[4];
    #pragma unroll
    for (int t = 0; t < 4; ++t) {
        int bb = __float_as_int(cz[t]);
        k[t]   = bb & 0x7fffffff;
        pay[t] = ((1023 - (tid * 4 + t)) << 1) | (int)((unsigned)bb >> 31);
    }

    if (!SEEDED) {
        int lm = max(max(k[0], k[1]), max(k[2], k[3]));
        #pragma unroll
        for (int k2 = 2; k2 <= 64; k2 <<= 1) {
            #pragma unroll
            for (int j = k2 >> 1; j > 0; j >>= 1) {
                int p = __shfl_xor(lm, j);
                bool keep_max = (((lane & k2) == 0) == ((lane & j) == 0));
                if ((p > lm) == keep_max) lm = p;
            }
        }
        int wb = __builtin_amdgcn_readlane(lm, 9);
        if (lane == 0) s_bnd[wid] = wb;
        __syncthreads();
        tbits = max(max(s_bnd[0], s_bnd[1]), max(s_bnd[2], s_bnd[3]));
    }

    int tb = tbits;
    int c0, c1, c2, c3, total; bool bad;
    #pragma unroll 1
    for (;;) {
        unsigned long long b0 = __ballot(k[0] >= tb);
        unsigned long long b1 = __ballot(k[1] >= tb);
        unsigned long long b2 = __ballot(k[2] >= tb);
        unsigned long long b3 = __ballot(k[3] >= tb);
        int pos = lt_count(b0);
        if (k[0] >= tb && pos < CAPW) s_cand[wid][pos] = make_int2(k[0], pay[0]);
        int base = __popcll(b0);
        pos = base + lt_count(b1);
        if (k[1] >= tb && pos < CAPW) s_cand[wid][pos] = make_int2(k[1], pay[1]);
        base += __popcll(b1);
        pos = base + lt_count(b2);
        if (k[2] >= tb && pos < CAPW) s_cand[wid][pos] = make_int2(k[2], pay[2]);
        base += __popcll(b2);
        pos = base + lt_count(b3);
        if (k[3] >= tb && pos < CAPW) s_cand[wid][pos] = make_int2(k[3], pay[3]);
        base += __popcll(b3);
        if (lane == 0) s_cnt[wid] = base;
        __syncthreads();                               // barrier 1
        c0 = s_cnt[0]; c1 = s_cnt[1]; c2 = s_cnt[2]; c3 = s_cnt[3];
        total = c0 + c1 + c2 + c3;
        bad = (c0 > CAPW) || (c1 > CAPW) || (c2 > CAPW) || (c3 > CAPW);
        if (total >= 10 || tb == 0) break;
        tb = (tb > 0x00800000) ? (tb - 0x00800000) : 0;
        __syncthreads();
    }

    if (!bad) {
        if (tid < total) {
            int w, e;
            if      (tid < c0)           { w = 0; e = tid; }
            else if (tid < c0 + c1)      { w = 1; e = tid - c0; }
            else if (tid < c0 + c1 + c2) { w = 2; e = tid - c0 - c1; }
            else                         { w = 3; e = tid - c0 - c1 - c2; }
            int2 mine = s_cand[w][e];
            int cns[4] = {c0, c1, c2, c3};
            int rank = 0;
            #pragma unroll
            for (int w2 = 0; w2 < 4; ++w2) {
                const int cn = cns[w2];
                const int2* reg = s_cand[w2];
                int e2 = 0;
                #pragma unroll 1
                for (; e2 + 4 <= cn; e2 += 4) {
                    int2 q0 = reg[e2], q1 = reg[e2+1], q2 = reg[e2+2], q3 = reg[e2+3];
                    rank += kp_gt(q0.x, q0.y, mine.x, mine.y) ? 1 : 0;
                    rank += kp_gt(q1.x, q1.y, mine.x, mine.y) ? 1 : 0;
                    rank += kp_gt(q2.x, q2.y, mine.x, mine.y) ? 1 : 0;
                    rank += kp_gt(q3.x, q3.y, mine.x, mine.y) ? 1 : 0;
                }
                #pragma unroll 1
                for (; e2 < cn; ++e2) {
                    int2 q = reg[e2];
                    rank += kp_gt(q.x, q.y, mine.x, mine.y) ? 1 : 0;
                }
            }
            if (rank < 10) s_win[rank] = mine;
        }
        __syncthreads();                               // barrier 2
    } else {
        #pragma unroll 1
        for (int r = 0; r < 10; ++r) {
            int bk = k[0], bp = pay[0];
            #pragma unroll
            for (int t = 1; t < 4; ++t)
                if (kp_gt(k[t], pay[t], bk, bp)) { bk = k[t]; bp = pay[t]; }
            #pragma unroll
            for (int m = 1; m < 64; m <<= 1) {
                int ok = __shfl_xor(bk, m), op = __shfl_xor(bp, m);
                if (kp_gt(ok, op, bk, bp)) { bk = ok; bp = op; }
            }
            if (lane == 0) s_red[wid] = make_int2(bk, bp);
            __syncthreads();
            if (tid == 0) {
                int2 best = s_red[0];
                #pragma unroll
                for (int w2 = 1; w2 < 4; ++w2) {
                    int2 cc = s_red[w2];
                    if (kp_gt(cc.x, cc.y, best.x, best.y)) best = cc;
                }
                s_win[r] = best;
            }
            __syncthreads();
            int2 wr = s_win[r];
            #pragma unroll
            for (int t = 0; t < 4; ++t)
                if (k[t] == wr.x && pay[t] == wr.y) k[t] = -1;
        }
    }

    #pragma unroll
    for (int r = 0; r < 10; ++r) {
        int2 wr = s_win[r];
        wi[r] = 1023 - (wr.y >> 1);
        wv[r] = __int_as_float(wr.x | ((wr.y & 1) << 31));
    }
    tbits = __float_as_int(wv[9]) & 0x7fffffff;
}

// c = b + sum_k wv[k] * S[wi[k], :]
__device__ __forceinline__ void gather_block(const float bz[4], float cz[4],
                                             const float* __restrict__ S,
                                             const int wi[10], const float wv[10], int tid)
{
    #pragma unroll
    for (int t = 0; t < 4; ++t) cz[t] = bz[t];
    #pragma unroll
    for (int kk = 0; kk < 10; ++kk) {
        int row = __builtin_amdgcn_readfirstlane(wi[kk]);
        const float wvs = wv[kk];
        float4 v = *(const float4*)(S + (size_t)row * DIM + tid * 4);
        cz[0] += wvs * v.x;
        cz[1] += wvs * v.y;
        cz[2] += wvs * v.z;
        cz[3] += wvs * v.w;
    }
}

// ============================================================================
// Warm-up rows
// ============================================================================
__global__ __launch_bounds__(256)
void warmup_rows(const float* __restrict__ b, const float* __restrict__ S,
                 int* __restrict__ sidx, float* __restrict__ sval)
{
    __shared__ int2 s_cand[4][CAPW];
    __shared__ int2 s_win[10];
    __shared__ int2 s_red[4];
    __shared__ int  s_cnt[4];
    __shared__ int  s_bnd[4];
    const int tid = threadIdx.x, lane = tid & 63, wid = tid >> 6;
    const int r = blockIdx.x;
    float4 bv = *(const float4*)(b + (size_t)r * DIM + tid * 4);
    float bz[4] = {bv.x, bv.y, bv.z, bv.w};
    int wi[10]; float wv[10]; int tbits = 0;
    select10_blk<false>(bz, tid, lane, wid, s_cand, s_win, s_cnt, s_red, s_bnd, tbits, wi, wv);
    float cz[4];
    gather_block(bz, cz, S, wi, wv, tid);
    select10_blk<true>(cz, tid, lane, wid, s_cand, s_win, s_cnt, s_red, s_bnd, tbits, wi, wv);
    if (tid < 10) {
        int2 wr = s_win[tid];
        sidx[r * 10 + tid] = 1023 - (wr.y >> 1);
        sval[r * 10 + tid] = __int_as_float(wr.x | ((wr.y & 1) << 31));
    }
}

// ============================================================================
// Main loop rows
// ============================================================================
__global__ __launch_bounds__(256)
void loop_rows(const float* __restrict__ c1, const float* __restrict__ b,
               const float* __restrict__ S, float* __restrict__ zout,
               int* __restrict__ sidx, float* __restrict__ sval)
{
    __shared__ int2 s_cand[4][CAPW];
    __shared__ int2 s_win[10];
    __shared__ int2 s_red[4];
    __shared__ int  s_cnt[4];
    __shared__ int  s_bnd[4];
    const int tid = threadIdx.x, lane = tid & 63, wid = tid >> 6;
    const int r = blockIdx.x;
    float4 bv = *(const float4*)(b  + (size_t)r * DIM + tid * 4);
    float4 cv = *(const float4*)(c1 + (size_t)r * DIM + tid * 4);
    float bz[4] = {bv.x, bv.y, bv.z, bv.w};
    float cz[4] = {cv.x, cv.y, cv.z, cv.w};
    int wi[10]; float wv[10]; int tbits = 0;
    select10_blk<false>(cz, tid, lane, wid, s_cand, s_win, s_cnt, s_red, s_bnd, tbits, wi, wv);
    int pwi[10], pwb[10];
    #pragma unroll 1
    for (int it = 0; it < 9; ++it) {
        #pragma unroll
        for (int kk = 0; kk < 10; ++kk) { pwi[kk] = wi[kk]; pwb[kk] = __float_as_int(wv[kk]); }
        gather_block(bz, cz, S, wi, wv, tid);
        select10_blk<true>(cz, tid, lane, wid, s_cand, s_win, s_cnt, s_red, s_bnd, tbits, wi, wv);
        bool same = true;
        #pragma unroll
        for (int kk = 0; kk < 10; ++kk)
            same = same && (wi[kk] == pwi[kk]) && (__float_as_int(wv[kk]) == pwb[kk]);
        if (same) break;
    }
    float e[4];
    #pragma unroll
    for (int t = 0; t < 4; ++t) {
        const int j = tid * 4 + t;
        float v = 0.0f;
        #pragma unroll
        for (int kk = 0; kk < 10; ++kk) v = (wi[kk] == j) ? wv[kk] : v;
        e[t] = v;
    }
    float4 o; o.x = e[0]; o.y = e[1]; o.z = e[2]; o.w = e[3];
    *(float4*)(zout + (size_t)r * DIM + tid * 4) = o;
    if (tid < 10) {
        int2 wr = s_win[tid];
        sidx[r * 10 + tid] = 1023 - (wr.y >> 1);
        sval[r * 10 + tid] = __int_as_float(wr.x | ((wr.y & 1) << 31));
    }
}

// ============================================================================
// GEMM: C[m,n] = (sum_k A[m,k]*B[n,k]) [/L] [+ add[m,n]]  (C = A @ B^T)
// ROUND-10 PROVEN CONFIG: 128x128 tile, BK=16, 512 threads = 8 waves (2x4
// wave grid, 8x8 lane grid, 8x4/thread), cmap conflict-free multicast LDS,
// double-buffered, ONE barrier per K-tile, register prefetch, grid 256.
// NO min-waves clause and NO BK=32 (both spilled: VGPR capped 64/128,
// GB of scratch traffic — rounds 11/12).
// NEW (zero-risk): XCD-aware 1D block swizzle — consecutive swizzled ids
// stay on one XCD so B-panels are L2-resident across neighbor tiles.
// ============================================================================
template<bool DIV_L, bool HAS_ADD>
__global__ __launch_bounds__(512)
void gemm512(const float* __restrict__ A, const float* __restrict__ B,
             const float* __restrict__ addM, float* __restrict__ C,
             const float* __restrict__ Lptr, int M, int N, int K)
{
    __shared__ __align__(16) float As[2][16][140];
    __shared__ __align__(16) float Bs[2][16][140];
    const int tid  = threadIdx.x;
    const int lane = tid & 63, w = tid >> 6;
    const int wy = lane >> 3, wx = lane & 7;
    const int mq = w >> 2, nq = w & 3;

    // XCD swizzle: nwg = gridDim.x (multiple of 8). swz = (bid%8)*(nwg/8)+bid/8
    const int nwg = gridDim.x;
    const int cpx = nwg >> 3;
    const int bid = blockIdx.x;
    const int swz = (bid & 7) * cpx + (bid >> 3);
    const int ntiles_n = N / 128;
    const int m0 = (swz / ntiles_n) * 128;
    const int n0 = (swz % ntiles_n) * 128;

    const int srow = tid >> 2;
    const int sk   = (tid & 3) * 4;
    const int scol = srow + ((srow >> 5) << 2);

    const int am_ = mq * 64 + wy * 8;
    const int aoff = am_ + ((am_ >> 5) << 2);
    const int bn_ = nq * 32 + wx * 4;
    const int boff = bn_ + ((bn_ >> 5) << 2);

    const float* Ab = A + (size_t)(m0 + srow) * K + sk;
    const float* Bb = B + (size_t)(n0 + srow) * K + sk;

    float acc[8][4] = {};

    float4 ra = *(const float4*)(Ab);
    float4 rb = *(const float4*)(Bb);

    const int NT = K / 16;
    {
        float* ap = &As[0][sk][scol];
        ap[0*140]=ra.x; ap[1*140]=ra.y; ap[2*140]=ra.z; ap[3*140]=ra.w;
        float* bp = &Bs[0][sk][scol];
        bp[0*140]=rb.x; bp[1*140]=rb.y; bp[2*140]=rb.z; bp[3*140]=rb.w;
    }
    __syncthreads();

    #pragma unroll 1
    for (int t = 0; t < NT; ++t) {
        const int cur = t & 1;
        if (t + 1 < NT) {
            const int ko = (t + 1) * 16;
            ra = *(const float4*)(Ab + ko);
            rb = *(const float4*)(Bb + ko);
        }
        #pragma unroll
        for (int k = 0; k < 16; ++k) {
            float4 a40 = *(const float4*)&As[cur][k][aoff];
            float4 a41 = *(const float4*)&As[cur][k][aoff + 4];
            float4 b40 = *(const float4*)&Bs[cur][k][boff];
            float am[8] = {a40.x,a40.y,a40.z,a40.w,a41.x,a41.y,a41.z,a41.w};
            float bn[4] = {b40.x,b40.y,b40.z,b40.w};
            #pragma unroll
            for (int i = 0; i < 8; ++i)
                #pragma unroll
                for (int j = 0; j < 4; ++j)
                    acc[i][j] += am[i] * bn[j];
        }
        if (t + 1 < NT) {
            const int nxt = (t + 1) & 1;
            float* ap = &As[nxt][sk][scol];
            ap[0*140]=ra.x; ap[1*140]=ra.y; ap[2*140]=ra.z; ap[3*140]=ra.w;
            float* bp = &Bs[nxt][sk][scol];
            bp[0*140]=rb.x; bp[1*140]=rb.y; bp[2*140]=rb.z; bp[3*140]=rb.w;
            __syncthreads();
        }
    }

    const float invL = DIV_L ? (1.0f / *Lptr) : 1.0f;
    #pragma unroll
    for (int i = 0; i < 8; ++i) {
        size_t row = (size_t)(m0 + mq*64 + wy*8 + i);
        float* Cp = C + row * N + n0 + nq*32 + wx*4;
        float4 rv;
        rv.x=acc[i][0]; rv.y=acc[i][1]; rv.z=acc[i][2]; rv.w=acc[i][3];
        if (DIV_L) { rv.x*=invL; rv.y*=invL; rv.z*=invL; rv.w*=invL; }
        if (HAS_ADD) {
            float4 ad = *(const float4*)(addM + row * N + n0 + nq*32 + wx*4);
            rv.x+=ad.x; rv.y+=ad.y; rv.z+=ad.z; rv.w+=ad.w;
        }
        *(float4*)(Cp) = rv;
    }
}

// ============================================================================
// Spectral density from sparse z
// ============================================================================
__global__ void sparse_density_stage1(const int* __restrict__ sidx,
                                      const float* __restrict__ sval,
                                      float* __restrict__ partial)
{
    const int w = threadIdx.x;
    const int blk = blockIdx.x;
    const int base = blk * 64 * 10;
    float acc = 0.0f;
    for (int e = 0; e < 640; ++e) {
        int d = sidx[base + e];
        float v = sval[base + e];
        if ((d & 511) == w) acc += v * v;
    }
    partial[blk * 512 + w] = acc;
}

// ============================================================================
// prev_windows spectral density
// ============================================================================
__global__ void prev_density_stage1(const float* __restrict__ pw, float* __restrict__ partial)
{
    const int p = blockIdx.x, chunk = blockIdx.y;
    const int w = threadIdx.x;
    const float* base = pw + ((size_t)p * BATCH + (size_t)chunk * 64) * DIM;
    float acc = 0.0f;
    for (int i = 0; i < 64; ++i) {
        float a = base[(size_t)i * DIM + w];
        float c = base[(size_t)i * DIM + 512 + w];
        acc += a * a + c * c;
    }
    partial[((size_t)(p * 64 + chunk)) * 512 + w] = acc;
}

__global__ void prev_density_stage2(const float* __restrict__ partial, float* __restrict__ mD_prev)
{
    const int p = blockIdx.x; const int w = threadIdx.x;
    float acc = 0.0f;
    for (int i = 0; i < 64; ++i) acc += partial[((size_t)(p * 64 + i)) * 512 + w];
    mD_prev[p * 512 + w] = acc;
}

// ============================================================================
// Fused: mD1 col-sum; normalize; attention logits; softmax.
// ============================================================================
__device__ __forceinline__ float wave_fmax(float v) {
    #pragma unroll
    for (int m = 1; m < 64; m <<= 1) v = fmaxf(v, __shfl_xor(v, m));
    return v;
}
__device__ __forceinline__ float wave_fmin(float v) {
    #pragma unroll
    for (int m = 1; m < 64; m <<= 1) v = fminf(v, __shfl_xor(v, m));
    return v;
}
__device__ __forceinline__ float wave_fsum(float v) {
    #pragma unroll
    for (int m = 1; m < 64; m <<= 1) v += __shfl_xor(v, m);
    return v;
}

__global__ void density2_attention(const float* __restrict__ partial,
                                   const float* __restrict__ mD_prev,
                                   float* __restrict__ att)
{
    __shared__ float md1[512];
    __shared__ float att_l[PPREV];
    const int tid = threadIdx.x, lane = tid & 63, w = tid >> 6;
    float v = 0.0f;
    for (int i = 0; i < 64; ++i) v += partial[i * 512 + tid];
    md1[tid] = v;
    __syncthreads();
    float t8[8], u8[8];
    {
        const float4* m4 = (const float4*)(&md1[lane * 8]);
        float4 a = m4[0], bq = m4[1];
        t8[0]=a.x; t8[1]=a.y; t8[2]=a.z; t8[3]=a.w; t8[4]=bq.x; t8[5]=bq.y; t8[6]=bq.z; t8[7]=bq.w;
        const float4* p4 = (const float4*)(mD_prev + w * 512 + lane * 8);
        float4 c = p4[0], d = p4[1];
        u8[0]=c.x; u8[1]=c.y; u8[2]=c.z; u8[3]=c.w; u8[4]=d.x; u8[5]=d.y; u8[6]=d.z; u8[7]=d.w;
    }
    float mx = t8[0], mn = t8[0], pmx = u8[0], pmn = u8[0];
    #pragma unroll
    for (int i = 1; i < 8; ++i) {
        mx = fmaxf(mx, t8[i]); mn = fminf(mn, t8[i]);
        pmx = fmaxf(pmx, u8[i]); pmn = fminf(pmn, u8[i]);
    }
    mx = wave_fmax(mx); mn = wave_fmin(mn);
    pmx = wave_fmax(pmx); pmn = wave_fmin(pmn);
    const float inv  = 1.0f / (mx - mn + 1e-8f);
    const float pinv = 1.0f / (pmx - pmn + 1e-8f);
    float dot = 0.0f;
    #pragma unroll
    for (int i = 0; i < 8; ++i) dot += ((u8[i] - pmn) * pinv) * ((t8[i] - mn) * inv);
    dot = wave_fsum(dot);
    if (lane == 0) att_l[w] = dot / 22.627417f;   // np.float32(sqrt(512))
    __syncthreads();
    if (tid == 0) {
        float m = att_l[0];
        #pragma unroll
        for (int p = 1; p < PPREV; ++p) m = fmaxf(m, att_l[p]);
        float e[PPREV], s = 0.0f;
        #pragma unroll
        for (int p = 0; p < PPREV; ++p) { e[p] = expf(att_l[p] - m); s += e[p]; }
        #pragma unroll
        for (int p = 0; p < PPREV; ++p) att[p] = e[p] / s;
    }
}

// ============================================================================
// z_att = lambda2 * sum_p clip(pw[p], +-150) * att[p]
// ============================================================================
__global__ __launch_bounds__(256)
void weighted_sum(const float* __restrict__ pw, const float* __restrict__ att,
                  const float* __restrict__ lam, float* __restrict__ zatt)
{
    const size_t i = ((size_t)blockIdx.x * 256 + threadIdx.x) * 4;
    const float l2 = *lam;
    float a[PPREV];
    #pragma unroll
    for (int p = 0; p < PPREV; ++p) a[p] = att[p];
    float4 acc = make_float4(0.f, 0.f, 0.f, 0.f);
    #pragma unroll
    for (int p = 0; p < PPREV; ++p) {
        float4 v = *(const float4*)(pw + (size_t)p * BATCH * DIM + i);
        v.x = fminf(fmaxf(v.x, -150.f), 150.f);
        v.y = fminf(fmaxf(v.y, -150.f), 150.f);
        v.z = fminf(fmaxf(v.z, -150.f), 150.f);
        v.w = fminf(fmaxf(v.w, -150.f), 150.f);
        acc.x += v.x * a[p]; acc.y += v.y * a[p]; acc.z += v.z * a[p]; acc.w += v.w * a[p];
    }
    acc.x *= l2; acc.y *= l2; acc.z *= l2; acc.w *= l2;
    *(float4*)(zatt + i) = acc;
}

// ============================================================================
// Final: mD2 col-sum + min-max normalize into out[0:512]
// ============================================================================
__global__ void finalize_fused(const float* __restrict__ partial, float* __restrict__ out)
{
    __shared__ float red[512];
    const int tid = threadIdx.x;
    float v = 0.0f;
    for (int i = 0; i < 64; ++i) v += partial[i * 512 + tid];
    red[tid] = v; __syncthreads();
    for (int off = 256; off > 0; off >>= 1) { if (tid < off) red[tid] = fmaxf(red[tid], red[tid+off]); __syncthreads(); }
    float mx = red[0]; __syncthreads();
    red[tid] = v; __syncthreads();
    for (int off = 256; off > 0; off >>= 1) { if (tid < off) red[tid] = fminf(red[tid], red[tid+off]); __syncthreads(); }
    float mn = red[0];
    out[tid] = (v - mn) / (mx - mn + 1e-8f);
}

// ============================================================================
extern "C" void kernel_launch(void* const* d_in, const int* in_sizes, int n_in,
                              void* d_out, int out_size, void* d_ws, size_t ws_size,
                              hipStream_t stream)
{
    const float* x   = (const float*)d_in[0];   // [4096,1024]
    const float* pw  = (const float*)d_in[1];   // [8,4096,1024]
    const float* Wd  = (const float*)d_in[2];   // [1,1024,1024]
    const float* S   = (const float*)d_in[3];   // [1,1024,1024] (numerically symmetric)
    const float* lam = (const float*)d_in[4];   // scalar
    const float* L   = (const float*)d_in[5];   // scalar
    float* out = (float*)d_out;                 // [512] ++ [4096*1024]

    const size_t NE = (size_t)BATCH * DIM;              // 4,194,304

    float* b       = (float*)d_ws;                      // NE
    float* zatt    = b + NE;                            // NE
    float* pp_prev = zatt + NE;                         // 262,144
    float* pp_dens = pp_prev + 262144;                  // 32,768
    float* mD_prev = pp_dens + 32768;                   // 4096
    float* attw    = mD_prev + 4096;                    // 8
    float* sval1   = attw + 8;                          // 40,960
    float* sval2   = sval1 + 40960;                     // 40,960
    int*   sidx1   = (int*)(sval2 + 40960);             // 40,960 ints
    int*   sidx2   = sidx1 + 40960;                     // 40,960 ints

    float* c1   = out + 512;
    float* zout = out + 512;

    const int ngemm = (DIM / 128) * (BATCH / 128);      // 256 blocks (1D, swizzled)

    gemm512<true,  false><<<ngemm, 512, 0, stream>>>(x, Wd, nullptr, b, L, BATCH, DIM, DIM);
    warmup_rows<<<BATCH, 256, 0, stream>>>(b, S, sidx1, sval1);
    sparse_density_stage1<<<64, 512, 0, stream>>>(sidx1, sval1, pp_dens);
    prev_density_stage1<<<dim3(PPREV, 64), 512, 0, stream>>>(pw, pp_prev);
    prev_density_stage2<<<PPREV, 512, 0, stream>>>(pp_prev, mD_prev);
    density2_attention<<<1, 512, 0, stream>>>(pp_dens, mD_prev, attw);
    weighted_sum<<<(int)(NE / 1024), 256, 0, stream>>>(pw, attw, lam, zatt);
    gemm512<false, true ><<<ngemm, 512, 0, stream>>>(zatt, S, b, c1, nullptr, BATCH, DIM, DIM);
    loop_rows<<<BATCH, 256, 0, stream>>>(c1, b, S, zout, sidx2, sval2);
    sparse_density_stage1<<<64, 512, 0, stream>>>(sidx2, sval2, pp_dens);
    finalize_fused<<<1, 512, 0, stream>>>(pp_dens, out);
}

// Round 14
// 516.484 us; speedup vs baseline: 5.5063x; 1.0026x over previous
//
#include <hip/hip_runtime.h>
#include <stdint.h>

#define BATCH 4096
#define DIM   1024
#define PPREV 8
#define CAPW  64    // per-wave candidate capacity

// popcount of mask over lanes strictly below the current lane
__device__ __forceinline__ int lt_count(unsigned long long m) {
    return __builtin_amdgcn_mbcnt_hi((unsigned)(m >> 32),
           __builtin_amdgcn_mbcnt_lo((unsigned)m, 0));
}
__device__ __forceinline__ bool kp_gt(int ak, int ap, int bk, int bp) {
    return (ak > bk) || (ak == bk && ap > bp);
}

// ============================================================================
// Block-cooperative top-10 by |value|, exact jax.lax.top_k tie-break (lowest
// flat index wins among ties). 128 threads/row (2 waves); thread owns
// j = tid*8+t. Key = |f32 bits| (int compare == magnitude compare);
// payload = ((1023-j)<<1)|sign -> (key,pay) lex-desc == (value desc, idx asc).
// ============================================================================
template<bool SEEDED>
__device__ __forceinline__ void select10_blk(
    const float cz[8], int tid, int lane, int wid,
    int2 (*s_cand)[CAPW], int2* s_win, int* s_cnt, int2* s_red, int* s_bnd,
    int& tbits, int wi[10], float wv[10])
{
    int k[8], pay[8];
    #pragma unroll
    for (int t = 0; t < 8; ++t) {
        int bb = __float_as_int(cz[t]);
        k[t]   = bb & 0x7fffffff;
        pay[t] = ((1023 - (tid * 8 + t)) << 1) | (int)((unsigned)bb >> 31);
    }

    if (!SEEDED) {
        // valid lower bound for the 10th-largest: per wave, the 10th-largest
        // of its 64 per-lane maxima (10 distinct lanes hold elements >= it);
        // block bound = max over the 2 waves (achieving wave = 10 witnesses).
        int lm = k[0];
        #pragma unroll
        for (int t = 1; t < 8; ++t) lm = max(lm, k[t]);
        #pragma unroll
        for (int k2 = 2; k2 <= 64; k2 <<= 1) {
            #pragma unroll
            for (int j = k2 >> 1; j > 0; j >>= 1) {
                int p = __shfl_xor(lm, j);
                bool keep_max = (((lane & k2) == 0) == ((lane & j) == 0));
                if ((p > lm) == keep_max) lm = p;
            }
        }
        int wb = __builtin_amdgcn_readlane(lm, 9);
        if (lane == 0) s_bnd[wid] = wb;
        __syncthreads();
        tbits = max(s_bnd[0], s_bnd[1]);
    }

    int tb = tbits;
    int c0, c1, total; bool bad;
    #pragma unroll 1
    for (;;) {
        int base = 0;
        #pragma unroll
        for (int t = 0; t < 8; ++t) {
            unsigned long long bs = __ballot(k[t] >= tb);
            int pos = base + lt_count(bs);
            if (k[t] >= tb && pos < CAPW) s_cand[wid][pos] = make_int2(k[t], pay[t]);
            base += __popcll(bs);
        }
        if (lane == 0) s_cnt[wid] = base;
        __syncthreads();                               // barrier 1
        c0 = s_cnt[0]; c1 = s_cnt[1];
        total = c0 + c1;
        bad = (c0 > CAPW) || (c1 > CAPW);
        if (total >= 10 || tb == 0) break;
        tb = (tb > 0x00800000) ? (tb - 0x00800000) : 0;   // halve threshold
        __syncthreads();   // protect s_cand/s_cnt rewrite from stragglers
    }

    if (!bad) {
        // exact rank by broadcast LDS reads (candidates distinct via pay)
        if (tid < total) {
            int w2 = (tid < c0) ? 0 : 1;
            int e  = (tid < c0) ? tid : tid - c0;
            int2 mine = s_cand[w2][e];
            int cns[2] = {c0, c1};
            int rank = 0;
            #pragma unroll
            for (int rg = 0; rg < 2; ++rg) {
                const int cn = cns[rg];
                const int2* reg = s_cand[rg];
                int e2 = 0;
                #pragma unroll 1
                for (; e2 + 4 <= cn; e2 += 4) {
                    int2 q0 = reg[e2], q1 = reg[e2+1], q2 = reg[e2+2], q3 = reg[e2+3];
                    rank += kp_gt(q0.x, q0.y, mine.x, mine.y) ? 1 : 0;
                    rank += kp_gt(q1.x, q1.y, mine.x, mine.y) ? 1 : 0;
                    rank += kp_gt(q2.x, q2.y, mine.x, mine.y) ? 1 : 0;
                    rank += kp_gt(q3.x, q3.y, mine.x, mine.y) ? 1 : 0;
                }
                #pragma unroll 1
                for (; e2 < cn; ++e2) {
                    int2 q = reg[e2];
                    rank += kp_gt(q.x, q.y, mine.x, mine.y) ? 1 : 0;
                }
            }
            if (rank < 10) s_win[rank] = mine;   // strict order -> unique ranks
        }
        __syncthreads();                               // barrier 2
    } else {
        // rare fallback: 10 rounds of exact block argmax (2 waves)
        #pragma unroll 1
        for (int r = 0; r < 10; ++r) {
            int bk = k[0], bp = pay[0];
            #pragma unroll
            for (int t = 1; t < 8; ++t)
                if (kp_gt(k[t], pay[t], bk, bp)) { bk = k[t]; bp = pay[t]; }
            #pragma unroll
            for (int m = 1; m < 64; m <<= 1) {
                int ok = __shfl_xor(bk, m), op = __shfl_xor(bp, m);
                if (kp_gt(ok, op, bk, bp)) { bk = ok; bp = op; }
            }
            if (lane == 0) s_red[wid] = make_int2(bk, bp);
            __syncthreads();
            if (tid == 0) {
                int2 best = s_red[0];
                int2 cc = s_red[1];
                if (kp_gt(cc.x, cc.y, best.x, best.y)) best = cc;
                s_win[r] = best;
            }
            __syncthreads();
            int2 wr = s_win[r];
            #pragma unroll
            for (int t = 0; t < 8; ++t)
                if (k[t] == wr.x && pay[t] == wr.y) k[t] = -1;   // pay unique
        }
    }

    #pragma unroll
    for (int r = 0; r < 10; ++r) {
        int2 wr = s_win[r];
        wi[r] = 1023 - (wr.y >> 1);
        wv[r] = __int_as_float(wr.x | ((wr.y & 1) << 31));
    }
    tbits = __float_as_int(wv[9]) & 0x7fffffff;
}

// c = b + sum_k wv[k] * S[wi[k], :]  (same per-element accumulation order as
// before -> bitwise-identical results; thread owns 8 contiguous elements)
__device__ __forceinline__ void gather_block8(const float bz[8], float cz[8],
                                              const float* __restrict__ S,
                                              const int wi[10], const float wv[10], int tid)
{
    #pragma unroll
    for (int t = 0; t < 8; ++t) cz[t] = bz[t];
    #pragma unroll
    for (int kk = 0; kk < 10; ++kk) {
        int row = __builtin_amdgcn_readfirstlane(wi[kk]);
        const float wvs = wv[kk];
        const float4* sp = (const float4*)(S + (size_t)row * DIM + tid * 8);
        float4 v0 = sp[0];
        float4 v1 = sp[1];
        cz[0] += wvs * v0.x; cz[1] += wvs * v0.y;
        cz[2] += wvs * v0.z; cz[3] += wvs * v0.w;
        cz[4] += wvs * v1.x; cz[5] += wvs * v1.y;
        cz[6] += wvs * v1.z; cz[7] += wvs * v1.w;
    }
}

// ============================================================================
// Warm-up: z=thr(b); c=b+z@S^T; z=thr(c) -> sparse (idx,val). 128 thr/row.
// ============================================================================
__global__ __launch_bounds__(128)
void warmup_rows(const float* __restrict__ b, const float* __restrict__ S,
                 int* __restrict__ sidx, float* __restrict__ sval)
{
    __shared__ int2 s_cand[2][CAPW];
    __shared__ int2 s_win[10];
    __shared__ int2 s_red[2];
    __shared__ int  s_cnt[2];
    __shared__ int  s_bnd[2];
    const int tid = threadIdx.x, lane = tid & 63, wid = tid >> 6;
    const int r = blockIdx.x;
    const float4* bp = (const float4*)(b + (size_t)r * DIM + tid * 8);
    float4 b0 = bp[0], b1 = bp[1];
    float bz[8] = {b0.x, b0.y, b0.z, b0.w, b1.x, b1.y, b1.z, b1.w};
    int wi[10]; float wv[10]; int tbits = 0;
    select10_blk<false>(bz, tid, lane, wid, s_cand, s_win, s_cnt, s_red, s_bnd, tbits, wi, wv);
    float cz[8];
    gather_block8(bz, cz, S, wi, wv, tid);
    select10_blk<true>(cz, tid, lane, wid, s_cand, s_win, s_cnt, s_red, s_bnd, tbits, wi, wv);
    if (tid < 10) {
        int2 wr = s_win[tid];
        sidx[r * 10 + tid] = 1023 - (wr.y >> 1);
        sval[r * 10 + tid] = __int_as_float(wr.x | ((wr.y & 1) << 31));
    }
}

// ============================================================================
// Main loop: z=thr(c1); 9 x { c=b+z@S^T; z=thr(c) } with exact fixed-point
// early exit. Writes dense z + sparse. 128 threads (2 waves) per row.
// ============================================================================
__global__ __launch_bounds__(128)
void loop_rows(const float* __restrict__ c1, const float* __restrict__ b,
               const float* __restrict__ S, float* __restrict__ zout,
               int* __restrict__ sidx, float* __restrict__ sval)
{
    __shared__ int2 s_cand[2][CAPW];
    __shared__ int2 s_win[10];
    __shared__ int2 s_red[2];
    __shared__ int  s_cnt[2];
    __shared__ int  s_bnd[2];
    const int tid = threadIdx.x, lane = tid & 63, wid = tid >> 6;
    const int r = blockIdx.x;
    const float4* bp = (const float4*)(b  + (size_t)r * DIM + tid * 8);
    const float4* cp = (const float4*)(c1 + (size_t)r * DIM + tid * 8);
    float4 b0 = bp[0], b1 = bp[1];
    float4 c0 = cp[0], c1v = cp[1];
    float bz[8] = {b0.x, b0.y, b0.z, b0.w, b1.x, b1.y, b1.z, b1.w};
    float cz[8] = {c0.x, c0.y, c0.z, c0.w, c1v.x, c1v.y, c1v.z, c1v.w};
    int wi[10]; float wv[10]; int tbits = 0;
    select10_blk<false>(cz, tid, lane, wid, s_cand, s_win, s_cnt, s_red, s_bnd, tbits, wi, wv);
    int pwi[10], pwb[10];
    #pragma unroll 1
    for (int it = 0; it < 9; ++it) {
        #pragma unroll
        for (int kk = 0; kk < 10; ++kk) { pwi[kk] = wi[kk]; pwb[kk] = __float_as_int(wv[kk]); }
        gather_block8(bz, cz, S, wi, wv, tid);
        select10_blk<true>(cz, tid, lane, wid, s_cand, s_win, s_cnt, s_red, s_bnd, tbits, wi, wv);
        bool same = true;
        #pragma unroll
        for (int kk = 0; kk < 10; ++kk)
            same = same && (wi[kk] == pwi[kk]) && (__float_as_int(wv[kk]) == pwb[kk]);
        if (same) break;   // exact fixed point: remaining iterations identical
    }
    float e[8];
    #pragma unroll
    for (int t = 0; t < 8; ++t) {
        const int j = tid * 8 + t;
        float v = 0.0f;
        #pragma unroll
        for (int kk = 0; kk < 10; ++kk) v = (wi[kk] == j) ? wv[kk] : v;
        e[t] = v;
    }
    float4* zp = (float4*)(zout + (size_t)r * DIM + tid * 8);
    float4 o0; o0.x = e[0]; o0.y = e[1]; o0.z = e[2]; o0.w = e[3];
    float4 o1; o1.x = e[4]; o1.y = e[5]; o1.z = e[6]; o1.w = e[7];
    zp[0] = o0;
    zp[1] = o1;
    if (tid < 10) {
        int2 wr = s_win[tid];
        sidx[r * 10 + tid] = 1023 - (wr.y >> 1);
        sval[r * 10 + tid] = __int_as_float(wr.x | ((wr.y & 1) << 31));
    }
}

// ============================================================================
// GEMM: C[m,n] = (sum_k A[m,k]*B[n,k]) [/L] [+ add[m,n]]  (C = A @ B^T)
// PROVEN CONFIG (round 13): 128x128 tile, BK=16, 512 threads = 8 waves (2x4
// wave grid, 8x8 lane grid, 8x4/thread), cmap conflict-free multicast LDS,
// double-buffered, ONE barrier per K-tile, register prefetch, XCD swizzle.
// DO NOT add min-waves clause or BK=32 (both spilled — rounds 11/12).
// ============================================================================
template<bool DIV_L, bool HAS_ADD>
__global__ __launch_bounds__(512)
void gemm512(const float* __restrict__ A, const float* __restrict__ B,
             const float* __restrict__ addM, float* __restrict__ C,
             const float* __restrict__ Lptr, int M, int N, int K)
{
    __shared__ __align__(16) float As[2][16][140];
    __shared__ __align__(16) float Bs[2][16][140];
    const int tid  = threadIdx.x;
    const int lane = tid & 63, w = tid >> 6;
    const int wy = lane >> 3, wx = lane & 7;
    const int mq = w >> 2, nq = w & 3;

    const int nwg = gridDim.x;
    const int cpx = nwg >> 3;
    const int bid = blockIdx.x;
    const int swz = (bid & 7) * cpx + (bid >> 3);
    const int ntiles_n = N / 128;
    const int m0 = (swz / ntiles_n) * 128;
    const int n0 = (swz % ntiles_n) * 128;

    const int srow = tid >> 2;
    const int sk   = (tid & 3) * 4;
    const int scol = srow + ((srow >> 5) << 2);

    const int am_ = mq * 64 + wy * 8;
    const int aoff = am_ + ((am_ >> 5) << 2);
    const int bn_ = nq * 32 + wx * 4;
    const int boff = bn_ + ((bn_ >> 5) << 2);

    const float* Ab = A + (size_t)(m0 + srow) * K + sk;
    const float* Bb = B + (size_t)(n0 + srow) * K + sk;

    float acc[8][4] = {};

    float4 ra = *(const float4*)(Ab);
    float4 rb = *(const float4*)(Bb);

    const int NT = K / 16;
    {
        float* ap = &As[0][sk][scol];
        ap[0*140]=ra.x; ap[1*140]=ra.y; ap[2*140]=ra.z; ap[3*140]=ra.w;
        float* bp = &Bs[0][sk][scol];
        bp[0*140]=rb.x; bp[1*140]=rb.y; bp[2*140]=rb.z; bp[3*140]=rb.w;
    }
    __syncthreads();

    #pragma unroll 1
    for (int t = 0; t < NT; ++t) {
        const int cur = t & 1;
        if (t + 1 < NT) {
            const int ko = (t + 1) * 16;
            ra = *(const float4*)(Ab + ko);
            rb = *(const float4*)(Bb + ko);
        }
        #pragma unroll
        for (int k = 0; k < 16; ++k) {
            float4 a40 = *(const float4*)&As[cur][k][aoff];
            float4 a41 = *(const float4*)&As[cur][k][aoff + 4];
            float4 b40 = *(const float4*)&Bs[cur][k][boff];
            float am[8] = {a40.x,a40.y,a40.z,a40.w,a41.x,a41.y,a41.z,a41.w};
            float bn[4] = {b40.x,b40.y,b40.z,b40.w};
            #pragma unroll
            for (int i = 0; i < 8; ++i)
                #pragma unroll
                for (int j = 0; j < 4; ++j)
                    acc[i][j] += am[i] * bn[j];
        }
        if (t + 1 < NT) {
            const int nxt = (t + 1) & 1;
            float* ap = &As[nxt][sk][scol];
            ap[0*140]=ra.x; ap[1*140]=ra.y; ap[2*140]=ra.z; ap[3*140]=ra.w;
            float* bp = &Bs[nxt][sk][scol];
            bp[0*140]=rb.x; bp[1*140]=rb.y; bp[2*140]=rb.z; bp[3*140]=rb.w;
            __syncthreads();
        }
    }

    const float invL = DIV_L ? (1.0f / *Lptr) : 1.0f;
    #pragma unroll
    for (int i = 0; i < 8; ++i) {
        size_t row = (size_t)(m0 + mq*64 + wy*8 + i);
        float* Cp = C + row * N + n0 + nq*32 + wx*4;
        float4 rv;
        rv.x=acc[i][0]; rv.y=acc[i][1]; rv.z=acc[i][2]; rv.w=acc[i][3];
        if (DIV_L) { rv.x*=invL; rv.y*=invL; rv.z*=invL; rv.w*=invL; }
        if (HAS_ADD) {
            float4 ad = *(const float4*)(addM + row * N + n0 + nq*32 + wx*4);
            rv.x+=ad.x; rv.y+=ad.y; rv.z+=ad.z; rv.w+=ad.w;
        }
        *(float4*)(Cp) = rv;
    }
}

// ============================================================================
// Spectral density from sparse z
// ============================================================================
__global__ void sparse_density_stage1(const int* __restrict__ sidx,
                                      const float* __restrict__ sval,
                                      float* __restrict__ partial)
{
    const int w = threadIdx.x;
    const int blk = blockIdx.x;
    const int base = blk * 64 * 10;
    float acc = 0.0f;
    for (int e = 0; e < 640; ++e) {
        int d = sidx[base + e];
        float v = sval[base + e];
        if ((d & 511) == w) acc += v * v;
    }
    partial[blk * 512 + w] = acc;
}

// ============================================================================
// prev_windows spectral density
// ============================================================================
__global__ void prev_density_stage1(const float* __restrict__ pw, float* __restrict__ partial)
{
    const int p = blockIdx.x, chunk = blockIdx.y;
    const int w = threadIdx.x;
    const float* base = pw + ((size_t)p * BATCH + (size_t)chunk * 64) * DIM;
    float acc = 0.0f;
    for (int i = 0; i < 64; ++i) {
        float a = base[(size_t)i * DIM + w];
        float c = base[(size_t)i * DIM + 512 + w];
        acc += a * a + c * c;
    }
    partial[((size_t)(p * 64 + chunk)) * 512 + w] = acc;
}

__global__ void prev_density_stage2(const float* __restrict__ partial, float* __restrict__ mD_prev)
{
    const int p = blockIdx.x; const int w = threadIdx.x;
    float acc = 0.0f;
    for (int i = 0; i < 64; ++i) acc += partial[((size_t)(p * 64 + i)) * 512 + w];
    mD_prev[p * 512 + w] = acc;
}

// ============================================================================
// Fused: mD1 col-sum; normalize; attention logits; softmax.
// ============================================================================
__device__ __forceinline__ float wave_fmax(float v) {
    #pragma unroll
    for (int m = 1; m < 64; m <<= 1) v = fmaxf(v, __shfl_xor(v, m));
    return v;
}
__device__ __forceinline__ float wave_fmin(float v) {
    #pragma unroll
    for (int m = 1; m < 64; m <<= 1) v = fminf(v, __shfl_xor(v, m));
    return v;
}
__device__ __forceinline__ float wave_fsum(float v) {
    #pragma unroll
    for (int m = 1; m < 64; m <<= 1) v += __shfl_xor(v, m);
    return v;
}

__global__ void density2_attention(const float* __restrict__ partial,
                                   const float* __restrict__ mD_prev,
                                   float* __restrict__ att)
{
    __shared__ float md1[512];
    __shared__ float att_l[PPREV];
    const int tid = threadIdx.x, lane = tid & 63, w = tid >> 6;
    float v = 0.0f;
    for (int i = 0; i < 64; ++i) v += partial[i * 512 + tid];
    md1[tid] = v;
    __syncthreads();
    float t8[8], u8[8];
    {
        const float4* m4 = (const float4*)(&md1[lane * 8]);
        float4 a = m4[0], bq = m4[1];
        t8[0]=a.x; t8[1]=a.y; t8[2]=a.z; t8[3]=a.w; t8[4]=bq.x; t8[5]=bq.y; t8[6]=bq.z; t8[7]=bq.w;
        const float4* p4 = (const float4*)(mD_prev + w * 512 + lane * 8);
        float4 c = p4[0], d = p4[1];
        u8[0]=c.x; u8[1]=c.y; u8[2]=c.z; u8[3]=c.w; u8[4]=d.x; u8[5]=d.y; u8[6]=d.z; u8[7]=d.w;
    }
    float mx = t8[0], mn = t8[0], pmx = u8[0], pmn = u8[0];
    #pragma unroll
    for (int i = 1; i < 8; ++i) {
        mx = fmaxf(mx, t8[i]); mn = fminf(mn, t8[i]);
        pmx = fmaxf(pmx, u8[i]); pmn = fminf(pmn, u8[i]);
    }
    mx = wave_fmax(mx); mn = wave_fmin(mn);
    pmx = wave_fmax(pmx); pmn = wave_fmin(pmn);
    const float inv  = 1.0f / (mx - mn + 1e-8f);
    const float pinv = 1.0f / (pmx - pmn + 1e-8f);
    float dot = 0.0f;
    #pragma unroll
    for (int i = 0; i < 8; ++i) dot += ((u8[i] - pmn) * pinv) * ((t8[i] - mn) * inv);
    dot = wave_fsum(dot);
    if (lane == 0) att_l[w] = dot / 22.627417f;   // np.float32(sqrt(512))
    __syncthreads();
    if (tid == 0) {
        float m = att_l[0];
        #pragma unroll
        for (int p = 1; p < PPREV; ++p) m = fmaxf(m, att_l[p]);
        float e[PPREV], s = 0.0f;
        #pragma unroll
        for (int p = 0; p < PPREV; ++p) { e[p] = expf(att_l[p] - m); s += e[p]; }
        #pragma unroll
        for (int p = 0; p < PPREV; ++p) att[p] = e[p] / s;
    }
}

// ============================================================================
// z_att = lambda2 * sum_p clip(pw[p], +-150) * att[p]
// ============================================================================
__global__ __launch_bounds__(256)
void weighted_sum(const float* __restrict__ pw, const float* __restrict__ att,
                  const float* __restrict__ lam, float* __restrict__ zatt)
{
    const size_t i = ((size_t)blockIdx.x * 256 + threadIdx.x) * 4;
    const float l2 = *lam;
    float a[PPREV];
    #pragma unroll
    for (int p = 0; p < PPREV; ++p) a[p] = att[p];
    float4 acc = make_float4(0.f, 0.f, 0.f, 0.f);
    #pragma unroll
    for (int p = 0; p < PPREV; ++p) {
        float4 v = *(const float4*)(pw + (size_t)p * BATCH * DIM + i);
        v.x = fminf(fmaxf(v.x, -150.f), 150.f);
        v.y = fminf(fmaxf(v.y, -150.f), 150.f);
        v.z = fminf(fmaxf(v.z, -150.f), 150.f);
        v.w = fminf(fmaxf(v.w, -150.f), 150.f);
        acc.x += v.x * a[p]; acc.y += v.y * a[p]; acc.z += v.z * a[p]; acc.w += v.w * a[p];
    }
    acc.x *= l2; acc.y *= l2; acc.z *= l2; acc.w *= l2;
    *(float4*)(zatt + i) = acc;
}

// ============================================================================
// Final: mD2 col-sum + min-max normalize into out[0:512]
// ============================================================================
__global__ void finalize_fused(const float* __restrict__ partial, float* __restrict__ out)
{
    __shared__ float red[512];
    const int tid = threadIdx.x;
    float v = 0.0f;
    for (int i = 0; i < 64; ++i) v += partial[i * 512 + tid];
    red[tid] = v; __syncthreads();
    for (int off = 256; off > 0; off >>= 1) { if (tid < off) red[tid] = fmaxf(red[tid], red[tid+off]); __syncthreads(); }
    float mx = red[0]; __syncthreads();
    red[tid] = v; __syncthreads();
    for (int off = 256; off > 0; off >>= 1) { if (tid < off) red[tid] = fminf(red[tid], red[tid+off]); __syncthreads(); }
    float mn = red[0];
    out[tid] = (v - mn) / (mx - mn + 1e-8f);
}

// ============================================================================
extern "C" void kernel_launch(void* const* d_in, const int* in_sizes, int n_in,
                              void* d_out, int out_size, void* d_ws, size_t ws_size,
                              hipStream_t stream)
{
    const float* x   = (const float*)d_in[0];   // [4096,1024]
    const float* pw  = (const float*)d_in[1];   // [8,4096,1024]
    const float* Wd  = (const float*)d_in[2];   // [1,1024,1024]
    const float* S   = (const float*)d_in[3];   // [1,1024,1024] (numerically symmetric)
    const float* lam = (const float*)d_in[4];   // scalar
    const float* L   = (const float*)d_in[5];   // scalar
    float* out = (float*)d_out;                 // [512] ++ [4096*1024]

    const size_t NE = (size_t)BATCH * DIM;              // 4,194,304

    float* b       = (float*)d_ws;                      // NE
    float* zatt    = b + NE;                            // NE
    float* pp_prev = zatt + NE;                         // 262,144
    float* pp_dens = pp_prev + 262144;                  // 32,768
    float* mD_prev = pp_dens + 32768;                   // 4096
    float* attw    = mD_prev + 4096;                    // 8
    float* sval1   = attw + 8;                          // 40,960
    float* sval2   = sval1 + 40960;                     // 40,960
    int*   sidx1   = (int*)(sval2 + 40960);             // 40,960 ints
    int*   sidx2   = sidx1 + 40960;                     // 40,960 ints

    float* c1   = out + 512;
    float* zout = out + 512;

    const int ngemm = (DIM / 128) * (BATCH / 128);      // 256 blocks (1D, swizzled)

    gemm512<true,  false><<<ngemm, 512, 0, stream>>>(x, Wd, nullptr, b, L, BATCH, DIM, DIM);
    warmup_rows<<<BATCH, 128, 0, stream>>>(b, S, sidx1, sval1);
    sparse_density_stage1<<<64, 512, 0, stream>>>(sidx1, sval1, pp_dens);
    prev_density_stage1<<<dim3(PPREV, 64), 512, 0, stream>>>(pw, pp_prev);
    prev_density_stage2<<<PPREV, 512, 0, stream>>>(pp_prev, mD_prev);
    density2_attention<<<1, 512, 0, stream>>>(pp_dens, mD_prev, attw);
    weighted_sum<<<(int)(NE / 1024), 256, 0, stream>>>(pw, attw, lam, zatt);
    gemm512<false, true ><<<ngemm, 512, 0, stream>>>(zatt, S, b, c1, nullptr, BATCH, DIM, DIM);
    loop_rows<<<BATCH, 128, 0, stream>>>(c1, b, S, zout, sidx2, sval2);
    sparse_density_stage1<<<64, 512, 0, stream>>>(sidx2, sval2, pp_dens);
    finalize_fused<<<1, 512, 0, stream>>>(pp_dens, out);
}